// Round 1
// baseline (11779.962 us; speedup 1.0000x reference)
//
#include <hip/hip_runtime.h>
#include <math.h>

#define D_MODEL 384
#define D_STATE 64
#define D_INNER 768
#define HEADDIM 96
#define NHEADS 8
#define CONV_DIM 896
#define D_IN_PROJ 1672
#define BATCH 8
#define SEQ 1024
#define ROWS (BATCH*SEQ)   /* 8192 */
#define NUM_LAYERS 6

__device__ __forceinline__ float softplus_f(float v){
  return v > 20.f ? v : log1pf(expf(v));
}
__device__ __forceinline__ float silu_f(float v){
  return v / (1.f + expf(-v));
}

/* ---------------- LayerNorm: one block (128 thr) per row of 384 ---------------- */
__global__ void ln_kernel(const float* __restrict__ x, const float* __restrict__ w,
                          const float* __restrict__ b, float* __restrict__ o){
  int r = blockIdx.x;
  int tid = threadIdx.x; /* 128 */
  const float* xr = x + (size_t)r*D_MODEL;
  float v[3];
  float s = 0.f, sq = 0.f;
  #pragma unroll
  for (int e=0;e<3;e++){ v[e]=xr[tid+128*e]; s+=v[e]; sq+=v[e]*v[e]; }
  __shared__ float reds[128], redq[128];
  reds[tid]=s; redq[tid]=sq; __syncthreads();
  for (int off=64; off>0; off>>=1){
    if (tid<off){ reds[tid]+=reds[tid+off]; redq[tid]+=redq[tid+off]; }
    __syncthreads();
  }
  float mu = reds[0]*(1.f/D_MODEL);
  float var = redq[0]*(1.f/D_MODEL) - mu*mu;
  var = var < 0.f ? 0.f : var;
  float rstd = rsqrtf(var + 1e-12f);
  float* orow = o + (size_t)r*D_MODEL;
  #pragma unroll
  for (int e=0;e<3;e++){ int c=tid+128*e; orow[c] = (v[e]-mu)*rstd*w[c] + b[c]; }
}

/* ---------------- fp32 tiled GEMM: C(MxN) = A(MxK) @ B(KxN), optional += ------- */
__global__ void gemm_kernel(const float* __restrict__ A, const float* __restrict__ B,
                            float* __restrict__ C, int M, int N, int K, int accum){
  __shared__ float As[16][64];
  __shared__ float Bs[16][64];
  int tx = threadIdx.x, ty = threadIdx.y;
  int tid = ty*16+tx;
  int m0 = blockIdx.y*64, n0 = blockIdx.x*64;
  float acc[4][4] = {};
  for (int k0=0;k0<K;k0+=16){
    #pragma unroll
    for (int idx=tid; idx<64*16; idx+=256){
      int m = idx>>4, k = idx&15;
      As[k][m] = A[(size_t)(m0+m)*K + k0+k];
    }
    #pragma unroll
    for (int idx=tid; idx<16*64; idx+=256){
      int k = idx>>6, n = idx&63;
      int gn = n0+n;
      Bs[k][n] = (gn<N) ? B[(size_t)(k0+k)*N + gn] : 0.f;
    }
    __syncthreads();
    #pragma unroll
    for (int k=0;k<16;k++){
      float4 a = *(const float4*)&As[k][ty*4];
      float4 bv = *(const float4*)&Bs[k][tx*4];
      float av[4] = {a.x,a.y,a.z,a.w};
      float bw[4] = {bv.x,bv.y,bv.z,bv.w};
      #pragma unroll
      for (int i=0;i<4;i++)
        #pragma unroll
        for (int j=0;j<4;j++)
          acc[i][j] = fmaf(av[i], bw[j], acc[i][j]);
    }
    __syncthreads();
  }
  #pragma unroll
  for (int i=0;i<4;i++){
    int gm = m0 + ty*4 + i;
    #pragma unroll
    for (int j=0;j<4;j++){
      int gn = n0 + tx*4 + j;
      if (gn < N){
        size_t off = (size_t)gm*N + gn;
        C[off] = accum ? (C[off] + acc[i][j]) : acc[i][j];
      }
    }
  }
}

/* ---------------- causal depthwise conv (k=4) + bias + silu -------------------- */
__global__ void conv_kernel(const float* __restrict__ zx, const float* __restrict__ cw,
                            const float* __restrict__ cb, float* __restrict__ o){
  int idx = blockIdx.x*256 + threadIdx.x;
  int c = idx % CONV_DIM;
  int l = (idx / CONV_DIM) % SEQ;
  int b = idx / (CONV_DIM*SEQ);
  const float* src = zx + (size_t)b*SEQ*D_IN_PROJ + D_INNER + c;
  float acc = cb[c];
  #pragma unroll
  for (int j=0;j<4;j++){
    int ls = l - 3 + j;
    if (ls >= 0) acc = fmaf(src[(size_t)ls*D_IN_PROJ], cw[c*4+j], acc);
  }
  o[idx] = silu_f(acc);
}

/* ---------------- SSD scan: one wave per (b,h,p); lane = state n --------------- */
__global__ void scan_kernel(const float* __restrict__ zx, const float* __restrict__ xbc,
                            const float* __restrict__ dt_bias, const float* __restrict__ A_log,
                            const float* __restrict__ D_skip, float* __restrict__ y){
  int wave = (blockIdx.x*blockDim.x + threadIdx.x) >> 6;
  int lane = threadIdx.x & 63;
  int p = wave % HEADDIM;
  int h = (wave / HEADDIM) % NHEADS;
  int b = wave / (HEADDIM*NHEADS);
  float A  = -expf(A_log[h]);
  float Dk = D_skip[h];
  float dtb = dt_bias[h];
  const float* dtp = zx  + (size_t)b*SEQ*D_IN_PROJ + (D_INNER+CONV_DIM) + h;
  const float* xp  = xbc + (size_t)b*SEQ*CONV_DIM + h*HEADDIM + p;
  const float* Bp  = xbc + (size_t)b*SEQ*CONV_DIM + D_INNER + lane;
  const float* Cp  = Bp + D_STATE;
  float* yp = y + (size_t)b*SEQ*D_INNER + h*HEADDIM + p;
  float hs = 0.f;
  for (int t=0;t<SEQ;t++){
    float dt = softplus_f(dtp[(size_t)t*D_IN_PROJ] + dtb);
    float dA = __expf(dt*A);
    float xv = xp[(size_t)t*CONV_DIM];
    float Bv = Bp[(size_t)t*CONV_DIM];
    float Cv = Cp[(size_t)t*CONV_DIM];
    hs = fmaf(dA, hs, dt*Bv*xv);
    float part = hs*Cv;
    #pragma unroll
    for (int off=32; off>0; off>>=1) part += __shfl_xor(part, off);
    if (lane==0) yp[(size_t)t*D_INNER] = fmaf(Dk, xv, part);
  }
}

/* ---------------- gate (y * silu(z)) + RMSNorm * norm_w ------------------------ */
__global__ void gatenorm_kernel(const float* __restrict__ yin, const float* __restrict__ zx,
                                const float* __restrict__ nw, float* __restrict__ yout){
  int r = blockIdx.x;
  int tid = threadIdx.x; /* 256 */
  const float* yr = yin + (size_t)r*D_INNER;
  const float* zr = zx  + (size_t)r*D_IN_PROJ;
  float g[3]; float sq = 0.f;
  #pragma unroll
  for (int e=0;e<3;e++){
    int c = tid + 256*e;
    float z = zr[c];
    float v = yr[c]*silu_f(z);
    g[e]=v; sq += v*v;
  }
  __shared__ float red[256];
  red[tid]=sq; __syncthreads();
  for (int off=128; off>0; off>>=1){
    if (tid<off) red[tid]+=red[tid+off];
    __syncthreads();
  }
  float rms = rsqrtf(red[0]*(1.f/D_INNER) + 1e-5f);
  float* orow = yout + (size_t)r*D_INNER;
  #pragma unroll
  for (int e=0;e<3;e++){ int c=tid+256*e; orow[c]=g[e]*rms*nw[c]; }
}

extern "C" void kernel_launch(void* const* d_in, const int* in_sizes, int n_in,
                              void* d_out, int out_size, void* d_ws, size_t ws_size,
                              hipStream_t stream){
  const float* x0      = (const float*)d_in[0];
  const float* ln_w    = (const float*)d_in[1];
  const float* ln_b    = (const float*)d_in[2];
  const float* W_in    = (const float*)d_in[3];
  const float* conv_w  = (const float*)d_in[4];
  const float* conv_b  = (const float*)d_in[5];
  const float* dt_bias = (const float*)d_in[6];
  const float* A_log   = (const float*)d_in[7];
  const float* D_skip  = (const float*)d_in[8];
  const float* norm_w  = (const float*)d_in[9];
  const float* W_out   = (const float*)d_in[10];
  float* out = (float*)d_out;

  /* workspace layout (fp32):
     zx   : ROWS x 1672  (54.8 MB)
     xbc  : ROWS x 896   (29.4 MB)
     ybuf : ROWS x 768   (25.2 MB)  -- also reused as hn (ROWS x 384) */
  float* zx   = (float*)d_ws;
  float* xbc  = zx  + (size_t)ROWS*D_IN_PROJ;
  float* ybuf = xbc + (size_t)ROWS*CONV_DIM;
  float* hn   = ybuf;

  hipMemcpyAsync(out, x0, (size_t)ROWS*D_MODEL*sizeof(float),
                 hipMemcpyDeviceToDevice, stream);

  for (int i=0;i<NUM_LAYERS;i++){
    ln_kernel<<<ROWS,128,0,stream>>>(out, ln_w+(size_t)i*D_MODEL, ln_b+(size_t)i*D_MODEL, hn);
    gemm_kernel<<<dim3((D_IN_PROJ+63)/64, ROWS/64), dim3(16,16), 0, stream>>>(
        hn, W_in + (size_t)i*D_MODEL*D_IN_PROJ, zx, ROWS, D_IN_PROJ, D_MODEL, 0);
    conv_kernel<<<(ROWS*CONV_DIM)/256, 256, 0, stream>>>(
        zx, conv_w + (size_t)i*CONV_DIM*4, conv_b + (size_t)i*CONV_DIM, xbc);
    scan_kernel<<<(BATCH*NHEADS*HEADDIM)/4, 256, 0, stream>>>(
        zx, xbc, dt_bias+(size_t)i*NHEADS, A_log+(size_t)i*NHEADS, D_skip+(size_t)i*NHEADS, ybuf);
    gatenorm_kernel<<<ROWS,256,0,stream>>>(ybuf, zx, norm_w+(size_t)i*D_INNER, ybuf);
    gemm_kernel<<<dim3((D_MODEL+63)/64, ROWS/64), dim3(16,16), 0, stream>>>(
        ybuf, W_out + (size_t)i*D_INNER*D_MODEL, out, ROWS, D_MODEL, D_INNER, 1);
  }
}

// Round 2
// 3208.949 us; speedup vs baseline: 3.6710x; 3.6710x over previous
//
#include <hip/hip_runtime.h>
#include <math.h>

#define D_MODEL 384
#define D_STATE 64
#define D_INNER 768
#define HEADDIM 96
#define NHEADS 8
#define CONV_DIM 896
#define D_IN_PROJ 1672
#define BATCH 8
#define SEQ 1024
#define ROWS (BATCH*SEQ)   /* 8192 */
#define NUM_LAYERS 6
#define NC 32              /* chunks */
#define CHUNK 32           /* timesteps per chunk */

__device__ __forceinline__ float softplus_f(float v){
  return v > 20.f ? v : log1pf(expf(v));
}
__device__ __forceinline__ float silu_f(float v){
  return v / (1.f + expf(-v));
}

/* ---------------- LayerNorm: one block (128 thr) per row of 384 ---------------- */
__global__ void ln_kernel(const float* __restrict__ x, const float* __restrict__ w,
                          const float* __restrict__ b, float* __restrict__ o){
  int r = blockIdx.x;
  int tid = threadIdx.x; /* 128 */
  const float* xr = x + (size_t)r*D_MODEL;
  float v[3];
  float s = 0.f, sq = 0.f;
  #pragma unroll
  for (int e=0;e<3;e++){ v[e]=xr[tid+128*e]; s+=v[e]; sq+=v[e]*v[e]; }
  __shared__ float reds[128], redq[128];
  reds[tid]=s; redq[tid]=sq; __syncthreads();
  for (int off=64; off>0; off>>=1){
    if (tid<off){ reds[tid]+=reds[tid+off]; redq[tid]+=redq[tid+off]; }
    __syncthreads();
  }
  float mu = reds[0]*(1.f/D_MODEL);
  float var = redq[0]*(1.f/D_MODEL) - mu*mu;
  var = var < 0.f ? 0.f : var;
  float rstd = rsqrtf(var + 1e-12f);
  float* orow = o + (size_t)r*D_MODEL;
  #pragma unroll
  for (int e=0;e<3;e++){ int c=tid+128*e; orow[c] = (v[e]-mu)*rstd*w[c] + b[c]; }
}

/* ---------------- fp32 tiled GEMM: C(MxN) = A(MxK) @ B(KxN), optional += ------- */
__global__ void gemm_kernel(const float* __restrict__ A, const float* __restrict__ B,
                            float* __restrict__ C, int M, int N, int K, int accum){
  __shared__ float As[16][64];
  __shared__ float Bs[16][64];
  int tx = threadIdx.x, ty = threadIdx.y;
  int tid = ty*16+tx;
  int m0 = blockIdx.y*64, n0 = blockIdx.x*64;
  float acc[4][4] = {};
  for (int k0=0;k0<K;k0+=16){
    #pragma unroll
    for (int idx=tid; idx<64*16; idx+=256){
      int m = idx>>4, k = idx&15;
      As[k][m] = A[(size_t)(m0+m)*K + k0+k];
    }
    #pragma unroll
    for (int idx=tid; idx<16*64; idx+=256){
      int k = idx>>6, n = idx&63;
      int gn = n0+n;
      Bs[k][n] = (gn<N) ? B[(size_t)(k0+k)*N + gn] : 0.f;
    }
    __syncthreads();
    #pragma unroll
    for (int k=0;k<16;k++){
      float4 a = *(const float4*)&As[k][ty*4];
      float4 bv = *(const float4*)&Bs[k][tx*4];
      float av[4] = {a.x,a.y,a.z,a.w};
      float bw[4] = {bv.x,bv.y,bv.z,bv.w};
      #pragma unroll
      for (int i=0;i<4;i++)
        #pragma unroll
        for (int j=0;j<4;j++)
          acc[i][j] = fmaf(av[i], bw[j], acc[i][j]);
    }
    __syncthreads();
  }
  #pragma unroll
  for (int i=0;i<4;i++){
    int gm = m0 + ty*4 + i;
    #pragma unroll
    for (int j=0;j<4;j++){
      int gn = n0 + tx*4 + j;
      if (gn < N){
        size_t off = (size_t)gm*N + gn;
        C[off] = accum ? (C[off] + acc[i][j]) : acc[i][j];
      }
    }
  }
}

/* ---------------- causal depthwise conv (k=4) + bias + silu -------------------- */
__global__ void conv_kernel(const float* __restrict__ zx, const float* __restrict__ cw,
                            const float* __restrict__ cb, float* __restrict__ o){
  int idx = blockIdx.x*256 + threadIdx.x;
  int c = idx % CONV_DIM;
  int l = (idx / CONV_DIM) % SEQ;
  int b = idx / (CONV_DIM*SEQ);
  const float* src = zx + (size_t)b*SEQ*D_IN_PROJ + D_INNER + c;
  float acc = cb[c];
  #pragma unroll
  for (int j=0;j<4;j++){
    int ls = l - 3 + j;
    if (ls >= 0) acc = fmaf(src[(size_t)ls*D_IN_PROJ], cw[c*4+j], acc);
  }
  o[idx] = silu_f(acc);
}

/* ---------------- precompute dt (softplus) and dA = exp(dt*A) per (b,h,t) ------ */
__global__ void dt_kernel(const float* __restrict__ zx, const float* __restrict__ dt_bias,
                          const float* __restrict__ A_log,
                          float* __restrict__ dtv, float* __restrict__ dAv){
  int idx = blockIdx.x*256 + threadIdx.x;          /* (b*8+h)*SEQ + t */
  int t = idx & (SEQ-1);
  int h = (idx >> 10) & 7;
  int b = idx >> 13;
  float raw = zx[(size_t)(b*SEQ + t)*D_IN_PROJ + (D_INNER+CONV_DIM) + h];
  float dt = softplus_f(raw + dt_bias[h]);
  float A  = -expf(A_log[h]);
  dtv[idx] = dt;
  dAv[idx] = __expf(dt*A);
}

/* ---------------- per-chunk decay product Dc[b][h][c] -------------------------- */
__global__ void decay_kernel(const float* __restrict__ dAv, float* __restrict__ Dc){
  int idx = blockIdx.x*256 + threadIdx.x;          /* (b*8+h)*NC + c, 2048 total */
  int c = idx & (NC-1);
  int bh = idx >> 5;
  const float* p = dAv + (size_t)bh*SEQ + c*CHUNK;
  float prod = 1.f;
  #pragma unroll
  for (int j=0;j<CHUNK;j++) prod *= p[j];
  Dc[idx] = prod;
}

/* ---------------- pass 1: chunk-local state S_c[p][n], zero init --------------- */
__global__ __launch_bounds__(256) void chunkstate_kernel(
    const float* __restrict__ xbc, const float* __restrict__ dtv,
    const float* __restrict__ dAv, float* __restrict__ S){
  __shared__ float4 Bsh[CHUNK*16];
  int tid = threadIdx.x;
  int bid = blockIdx.x;                 /* 8 b * NC c * 3 parts */
  int part = bid % 3;
  int c = (bid/3) % NC;
  int b = bid / (3*NC);
  int t0 = c*CHUNK;
  for (int i = tid; i < CHUNK*16; i += 256){
    int t = i >> 4, q = i & 15;
    const float4* src = (const float4*)(xbc + ((size_t)(b*SEQ + t0 + t)*CONV_DIM + D_INNER));
    Bsh[i] = src[q];
  }
  __syncthreads();
  int u = part*256 + tid;               /* 0..767 = h*96+p */
  int h = u / 96, p = u % 96;
  const float* dtp = dtv + (size_t)(b*NHEADS + h)*SEQ + t0;
  const float* dAp = dAv + (size_t)(b*NHEADS + h)*SEQ + t0;
  const float* xp  = xbc + (size_t)(b*SEQ + t0)*CONV_DIM + h*HEADDIM + p;
  float hS[64];
  #pragma unroll
  for (int n=0;n<64;n++) hS[n]=0.f;
  for (int t=0;t<CHUNK;t++){
    float dt = dtp[t], dA = dAp[t];
    float xv = xp[(size_t)t*CONV_DIM];
    float ax = dt*xv;
    #pragma unroll
    for (int q=0;q<16;q++){
      float4 Bq = Bsh[t*16+q];
      hS[4*q+0] = fmaf(dA, hS[4*q+0], ax*Bq.x);
      hS[4*q+1] = fmaf(dA, hS[4*q+1], ax*Bq.y);
      hS[4*q+2] = fmaf(dA, hS[4*q+2], ax*Bq.z);
      hS[4*q+3] = fmaf(dA, hS[4*q+3], ax*Bq.w);
    }
  }
  float4* Sp = (float4*)S + ((((size_t)b*NC + c)*NHEADS + h)*96 + p)*16;
  #pragma unroll
  for (int q=0;q<16;q++)
    Sp[q] = make_float4(hS[4*q],hS[4*q+1],hS[4*q+2],hS[4*q+3]);
}

/* ---------------- pass 2: sequential chunk combine; S becomes Hin (in-place) --- */
__global__ __launch_bounds__(256) void combine_kernel(
    float* __restrict__ S, const float* __restrict__ Dc){
  int g = blockIdx.x*256 + threadIdx.x;     /* (b,h,p,nq): 8*8*96*16 = 98304 */
  int nq = g & 15;
  int p  = (g >> 4) % 96;
  int h  = (g / (16*96)) & 7;
  int b  = g / (16*96*8);
  float4* S4 = (float4*)S;
  const float* Dp = Dc + (size_t)(b*NHEADS + h)*NC;
  float4 H = make_float4(0.f,0.f,0.f,0.f);
  for (int c=0;c<NC;c++){
    size_t base = ((((size_t)b*NC + c)*NHEADS + h)*96 + p)*16 + nq;
    float4 s = S4[base];
    S4[base] = H;                     /* Hin for chunk c = state before chunk c */
    float D = Dp[c];
    H.x = fmaf(D, H.x, s.x);
    H.y = fmaf(D, H.y, s.y);
    H.z = fmaf(D, H.z, s.z);
    H.w = fmaf(D, H.w, s.w);
  }
}

/* ---------------- pass 3: re-scan chunk from Hin, emit y ----------------------- */
__global__ __launch_bounds__(256) void chunkout_kernel(
    const float* __restrict__ xbc, const float* __restrict__ dtv,
    const float* __restrict__ dAv, const float* __restrict__ Hin,
    const float* __restrict__ D_skip, float* __restrict__ y){
  __shared__ float4 Bsh[CHUNK*16];
  __shared__ float4 Csh[CHUNK*16];
  int tid = threadIdx.x;
  int bid = blockIdx.x;
  int part = bid % 3;
  int c = (bid/3) % NC;
  int b = bid / (3*NC);
  int t0 = c*CHUNK;
  for (int i = tid; i < CHUNK*16; i += 256){
    int t = i >> 4, q = i & 15;
    const float4* src = (const float4*)(xbc + ((size_t)(b*SEQ + t0 + t)*CONV_DIM + D_INNER));
    Bsh[i] = src[q];
    Csh[i] = src[q+16];               /* C starts 64 floats (16 float4) after B */
  }
  __syncthreads();
  int u = part*256 + tid;
  int h = u / 96, p = u % 96;
  const float* dtp = dtv + (size_t)(b*NHEADS + h)*SEQ + t0;
  const float* dAp = dAv + (size_t)(b*NHEADS + h)*SEQ + t0;
  const float* xp  = xbc + (size_t)(b*SEQ + t0)*CONV_DIM + h*HEADDIM + p;
  float* yp = y + (size_t)(b*SEQ + t0)*D_INNER + h*HEADDIM + p;
  float Dk = D_skip[h];
  float hS[64];
  const float4* Hp = (const float4*)Hin + ((((size_t)b*NC + c)*NHEADS + h)*96 + p)*16;
  #pragma unroll
  for (int q=0;q<16;q++){
    float4 v = Hp[q];
    hS[4*q]=v.x; hS[4*q+1]=v.y; hS[4*q+2]=v.z; hS[4*q+3]=v.w;
  }
  for (int t=0;t<CHUNK;t++){
    float dt = dtp[t], dA = dAp[t];
    float xv = xp[(size_t)t*CONV_DIM];
    float ax = dt*xv;
    float y0=0.f,y1=0.f,y2=0.f,y3=0.f;
    #pragma unroll
    for (int q=0;q<16;q++){
      float4 Bq = Bsh[t*16+q];
      float4 Cq = Csh[t*16+q];
      hS[4*q+0] = fmaf(dA, hS[4*q+0], ax*Bq.x); y0 = fmaf(hS[4*q+0], Cq.x, y0);
      hS[4*q+1] = fmaf(dA, hS[4*q+1], ax*Bq.y); y1 = fmaf(hS[4*q+1], Cq.y, y1);
      hS[4*q+2] = fmaf(dA, hS[4*q+2], ax*Bq.z); y2 = fmaf(hS[4*q+2], Cq.z, y2);
      hS[4*q+3] = fmaf(dA, hS[4*q+3], ax*Bq.w); y3 = fmaf(hS[4*q+3], Cq.w, y3);
    }
    yp[(size_t)t*D_INNER] = fmaf(Dk, xv, (y0+y1)+(y2+y3));
  }
}

/* ---------------- gate (y * silu(z)) + RMSNorm * norm_w ------------------------ */
__global__ void gatenorm_kernel(const float* __restrict__ yin, const float* __restrict__ zx,
                                const float* __restrict__ nw, float* __restrict__ yout){
  int r = blockIdx.x;
  int tid = threadIdx.x; /* 256 */
  const float* yr = yin + (size_t)r*D_INNER;
  const float* zr = zx  + (size_t)r*D_IN_PROJ;
  float g[3]; float sq = 0.f;
  #pragma unroll
  for (int e=0;e<3;e++){
    int c = tid + 256*e;
    float z = zr[c];
    float v = yr[c]*silu_f(z);
    g[e]=v; sq += v*v;
  }
  __shared__ float red[256];
  red[tid]=sq; __syncthreads();
  for (int off=128; off>0; off>>=1){
    if (tid<off) red[tid]+=red[tid+off];
    __syncthreads();
  }
  float rms = rsqrtf(red[0]*(1.f/D_INNER) + 1e-5f);
  float* orow = yout + (size_t)r*D_INNER;
  #pragma unroll
  for (int e=0;e<3;e++){ int c=tid+256*e; orow[c]=g[e]*rms*nw[c]; }
}

extern "C" void kernel_launch(void* const* d_in, const int* in_sizes, int n_in,
                              void* d_out, int out_size, void* d_ws, size_t ws_size,
                              hipStream_t stream){
  const float* x0      = (const float*)d_in[0];
  const float* ln_w    = (const float*)d_in[1];
  const float* ln_b    = (const float*)d_in[2];
  const float* W_in    = (const float*)d_in[3];
  const float* conv_w  = (const float*)d_in[4];
  const float* conv_b  = (const float*)d_in[5];
  const float* dt_bias = (const float*)d_in[6];
  const float* A_log   = (const float*)d_in[7];
  const float* D_skip  = (const float*)d_in[8];
  const float* norm_w  = (const float*)d_in[9];
  const float* W_out   = (const float*)d_in[10];
  float* out = (float*)d_out;

  /* workspace (floats):
     zx   : 8192 x 1672   = 13.70M
     xbc  : 8192 x 896    =  7.34M
     ybuf : 8192 x 768    =  6.29M  (reused as hn 8192x384)
     dtv  : 64 x 1024
     dAv  : 64 x 1024
     Dc   : 64 x 32
     Sbuf : 8 x 32 x 8 x 96 x 64 = 12.58M   (S, then Hin in-place)
     total ~160 MB */
  float* zx   = (float*)d_ws;
  float* xbc  = zx   + (size_t)ROWS*D_IN_PROJ;
  float* ybuf = xbc  + (size_t)ROWS*CONV_DIM;
  float* hn   = ybuf;
  float* dtv  = ybuf + (size_t)ROWS*D_INNER;
  float* dAv  = dtv  + (size_t)BATCH*NHEADS*SEQ;
  float* Dc   = dAv  + (size_t)BATCH*NHEADS*SEQ;
  float* Sbuf = Dc   + (size_t)BATCH*NHEADS*NC;

  hipMemcpyAsync(out, x0, (size_t)ROWS*D_MODEL*sizeof(float),
                 hipMemcpyDeviceToDevice, stream);

  for (int i=0;i<NUM_LAYERS;i++){
    ln_kernel<<<ROWS,128,0,stream>>>(out, ln_w+(size_t)i*D_MODEL, ln_b+(size_t)i*D_MODEL, hn);
    gemm_kernel<<<dim3((D_IN_PROJ+63)/64, ROWS/64), dim3(16,16), 0, stream>>>(
        hn, W_in + (size_t)i*D_MODEL*D_IN_PROJ, zx, ROWS, D_IN_PROJ, D_MODEL, 0);
    conv_kernel<<<(ROWS*CONV_DIM)/256, 256, 0, stream>>>(
        zx, conv_w + (size_t)i*CONV_DIM*4, conv_b + (size_t)i*CONV_DIM, xbc);
    dt_kernel<<<(BATCH*NHEADS*SEQ)/256, 256, 0, stream>>>(
        zx, dt_bias+(size_t)i*NHEADS, A_log+(size_t)i*NHEADS, dtv, dAv);
    decay_kernel<<<(BATCH*NHEADS*NC)/256, 256, 0, stream>>>(dAv, Dc);
    chunkstate_kernel<<<BATCH*NC*3, 256, 0, stream>>>(xbc, dtv, dAv, Sbuf);
    combine_kernel<<<(BATCH*NHEADS*96*16)/256, 256, 0, stream>>>(Sbuf, Dc);
    chunkout_kernel<<<BATCH*NC*3, 256, 0, stream>>>(
        xbc, dtv, dAv, Sbuf, D_skip+(size_t)i*NHEADS, ybuf);
    gatenorm_kernel<<<ROWS,256,0,stream>>>(ybuf, zx, norm_w+(size_t)i*D_INNER, ybuf);
    gemm_kernel<<<dim3((D_MODEL+63)/64, ROWS/64), dim3(16,16), 0, stream>>>(
        ybuf, W_out + (size_t)i*D_INNER*D_MODEL, out, ROWS, D_MODEL, D_INNER, 1);
  }
}

// Round 3
// 1502.444 us; speedup vs baseline: 7.8405x; 2.1358x over previous
//
#include <hip/hip_runtime.h>
#include <hip/hip_bf16.h>
#include <math.h>

#define D_MODEL 384
#define D_STATE 64
#define D_INNER 768
#define HEADDIM 96
#define NHEADS 8
#define CONV_DIM 896
#define D_IN_PROJ 1672
#define BATCH 8
#define SEQ 1024
#define ROWS (BATCH*SEQ)   /* 8192 */
#define NUM_LAYERS 6
#define NC 32              /* chunks */
#define CHUNK 32           /* timesteps per chunk */
#define NPAD_IN 1792       /* 14 * 128 */
#define NPAD_OUT 384       /* 3 * 128  */

typedef __hip_bfloat16 bf16;
using bf16x8_t = __attribute__((ext_vector_type(8))) short;
using f32x4_t  = __attribute__((ext_vector_type(4))) float;

__device__ __forceinline__ float softplus_f(float v){
  return v > 20.f ? v : log1pf(expf(v));
}
__device__ __forceinline__ float silu_f(float v){
  return v / (1.f + expf(-v));
}

/* ------------- weight transpose + fp32->bf16: W[K][N] -> Wt[Npad][K] ----------- */
__global__ void wconv_kernel(const float* __restrict__ W, bf16* __restrict__ Wt,
                             int K, int N, int Npad){
  __shared__ float tile[32][33];
  int kb = blockIdx.y*32, nb = blockIdx.x*32;
  int tx = threadIdx.x, ty = threadIdx.y;   /* 32 x 8 */
  #pragma unroll
  for (int r=0;r<32;r+=8){
    int k = kb+ty+r, n = nb+tx;
    tile[ty+r][tx] = (k<K && n<N) ? W[(size_t)k*N+n] : 0.f;
  }
  __syncthreads();
  #pragma unroll
  for (int r=0;r<32;r+=8){
    int n = nb+ty+r, k = kb+tx;
    if (n<Npad && k<K) Wt[(size_t)n*K+k] = __float2bfloat16(tile[tx][ty+r]);
  }
}

/* ---------------- LayerNorm: one block (128 thr) per row of 384 -> bf16 -------- */
__global__ void ln_kernel(const float* __restrict__ x, const float* __restrict__ w,
                          const float* __restrict__ b, bf16* __restrict__ o){
  int r = blockIdx.x;
  int tid = threadIdx.x; /* 128 */
  const float* xr = x + (size_t)r*D_MODEL;
  float v[3];
  float s = 0.f, sq = 0.f;
  #pragma unroll
  for (int e=0;e<3;e++){ v[e]=xr[tid+128*e]; s+=v[e]; sq+=v[e]*v[e]; }
  __shared__ float reds[128], redq[128];
  reds[tid]=s; redq[tid]=sq; __syncthreads();
  for (int off=64; off>0; off>>=1){
    if (tid<off){ reds[tid]+=reds[tid+off]; redq[tid]+=redq[tid+off]; }
    __syncthreads();
  }
  float mu = reds[0]*(1.f/D_MODEL);
  float var = redq[0]*(1.f/D_MODEL) - mu*mu;
  var = var < 0.f ? 0.f : var;
  float rstd = rsqrtf(var + 1e-12f);
  bf16* orow = o + (size_t)r*D_MODEL;
  #pragma unroll
  for (int e=0;e<3;e++){
    int c=tid+128*e;
    orow[c] = __float2bfloat16((v[e]-mu)*rstd*w[c] + b[c]);
  }
}

/* ---------------- bf16 MFMA GEMM: C(MxN) = A(MxK) @ Bt(NxK)^T ------------------ */
/* BM=BN=128, BK=32, 256 thr = 4 waves of 64x64; m97-style global_load_lds. */
template<int ACCUM>
__global__ __launch_bounds__(256) void mfma_gemm(
    const unsigned short* __restrict__ A,   /* M x K bf16, row-major */
    const unsigned short* __restrict__ Bt,  /* Npad x K bf16 (B transposed) */
    float* __restrict__ C,                  /* M x ldc fp32 */
    int N, int K, int ldc){
  __shared__ __align__(16) unsigned short As[128*32];
  __shared__ __align__(16) unsigned short Bs[128*32];
  const int tid = threadIdx.x;
  const int wave = tid >> 6, lane = tid & 63;
  const int lq = lane >> 4, lm = lane & 15;
  const int m0 = blockIdx.y * 128, n0 = blockIdx.x * 128;
  const int wm = (wave >> 1) * 64, wn = (wave & 1) * 64;
  f32x4_t acc[4][4];
  #pragma unroll
  for (int i=0;i<4;i++)
    #pragma unroll
    for (int j=0;j<4;j++)
      acc[i][j] = (f32x4_t){0.f,0.f,0.f,0.f};

  for (int k0 = 0; k0 < K; k0 += 32){
    if (k0) __syncthreads();               /* all waves done reading prev tile */
    #pragma unroll
    for (int q=0;q<2;q++){
      int o = q*4096 + wave*1024 + lane*16;   /* byte offset in 8 KB tile */
      int m = o >> 6;                          /* 64 B per [row][BK] row */
      int kb = o & 63;
      const unsigned short* ga = A  + (size_t)(m0+m)*K + k0 + (kb>>1);
      __builtin_amdgcn_global_load_lds(
          (const __attribute__((address_space(1))) void*)ga,
          (__attribute__((address_space(3))) void*)((char*)As + o), 16, 0, 0);
      const unsigned short* gb = Bt + (size_t)(n0+m)*K + k0 + (kb>>1);
      __builtin_amdgcn_global_load_lds(
          (const __attribute__((address_space(1))) void*)gb,
          (__attribute__((address_space(3))) void*)((char*)Bs + o), 16, 0, 0);
    }
    __syncthreads();                        /* drains vmcnt: tiles ready */
    bf16x8_t af[4], bfv[4];
    #pragma unroll
    for (int i=0;i<4;i++)
      af[i]  = *(const bf16x8_t*)(As + (wm + i*16 + lm)*32 + lq*8);
    #pragma unroll
    for (int j=0;j<4;j++)
      bfv[j] = *(const bf16x8_t*)(Bs + (wn + j*16 + lm)*32 + lq*8);
    #pragma unroll
    for (int i=0;i<4;i++)
      #pragma unroll
      for (int j=0;j<4;j++)
        acc[i][j] = __builtin_amdgcn_mfma_f32_16x16x32_bf16(af[i], bfv[j], acc[i][j], 0, 0, 0);
  }
  /* epilogue: C/D layout col=lane&15, row=(lane>>4)*4+reg */
  #pragma unroll
  for (int i=0;i<4;i++){
    int row = m0 + wm + i*16 + lq*4;
    #pragma unroll
    for (int j=0;j<4;j++){
      int col = n0 + wn + j*16 + lm;
      if (col < N){
        float* cp = C + (size_t)row*ldc + col;
        #pragma unroll
        for (int r=0;r<4;r++){
          if (ACCUM) cp[(size_t)r*ldc] += acc[i][j][r];
          else       cp[(size_t)r*ldc]  = acc[i][j][r];
        }
      }
    }
  }
}

/* ---------------- causal depthwise conv (k=4) + bias + silu -------------------- */
__global__ void conv_kernel(const float* __restrict__ zx, const float* __restrict__ cw,
                            const float* __restrict__ cb, float* __restrict__ o){
  int idx = blockIdx.x*256 + threadIdx.x;
  int c = idx % CONV_DIM;
  int l = (idx / CONV_DIM) % SEQ;
  int b = idx / (CONV_DIM*SEQ);
  const float* src = zx + (size_t)b*SEQ*D_IN_PROJ + D_INNER + c;
  float acc = cb[c];
  #pragma unroll
  for (int j=0;j<4;j++){
    int ls = l - 3 + j;
    if (ls >= 0) acc = fmaf(src[(size_t)ls*D_IN_PROJ], cw[c*4+j], acc);
  }
  o[idx] = silu_f(acc);
}

/* ---------------- precompute dt (softplus) and dA = exp(dt*A) per (b,h,t) ------ */
__global__ void dt_kernel(const float* __restrict__ zx, const float* __restrict__ dt_bias,
                          const float* __restrict__ A_log,
                          float* __restrict__ dtv, float* __restrict__ dAv){
  int idx = blockIdx.x*256 + threadIdx.x;          /* (b*8+h)*SEQ + t */
  int t = idx & (SEQ-1);
  int h = (idx >> 10) & 7;
  int b = idx >> 13;
  float raw = zx[(size_t)(b*SEQ + t)*D_IN_PROJ + (D_INNER+CONV_DIM) + h];
  float dt = softplus_f(raw + dt_bias[h]);
  float A  = -expf(A_log[h]);
  dtv[idx] = dt;
  dAv[idx] = __expf(dt*A);
}

/* ---------------- per-chunk decay product Dc[b][h][c] -------------------------- */
__global__ void decay_kernel(const float* __restrict__ dAv, float* __restrict__ Dc){
  int idx = blockIdx.x*256 + threadIdx.x;          /* (b*8+h)*NC + c, 2048 total */
  int c = idx & (NC-1);
  int bh = idx >> 5;
  const float* p = dAv + (size_t)bh*SEQ + c*CHUNK;
  float prod = 1.f;
  #pragma unroll
  for (int j=0;j<CHUNK;j++) prod *= p[j];
  Dc[idx] = prod;
}

/* ---------------- pass 1: chunk-local state S_c[p][n], zero init --------------- */
__global__ __launch_bounds__(256) void chunkstate_kernel(
    const float* __restrict__ xbc, const float* __restrict__ dtv,
    const float* __restrict__ dAv, float* __restrict__ S){
  __shared__ float4 Bsh[CHUNK*16];
  int tid = threadIdx.x;
  int bid = blockIdx.x;                 /* 8 b * NC c * 3 parts */
  int part = bid % 3;
  int c = (bid/3) % NC;
  int b = bid / (3*NC);
  int t0 = c*CHUNK;
  for (int i = tid; i < CHUNK*16; i += 256){
    int t = i >> 4, q = i & 15;
    const float4* src = (const float4*)(xbc + ((size_t)(b*SEQ + t0 + t)*CONV_DIM + D_INNER));
    Bsh[i] = src[q];
  }
  __syncthreads();
  int u = part*256 + tid;               /* 0..767 = h*96+p */
  int h = u / 96, p = u % 96;
  const float* dtp = dtv + (size_t)(b*NHEADS + h)*SEQ + t0;
  const float* dAp = dAv + (size_t)(b*NHEADS + h)*SEQ + t0;
  const float* xp  = xbc + (size_t)(b*SEQ + t0)*CONV_DIM + h*HEADDIM + p;
  float hS[64];
  #pragma unroll
  for (int n=0;n<64;n++) hS[n]=0.f;
  for (int t=0;t<CHUNK;t++){
    float dt = dtp[t], dA = dAp[t];
    float xv = xp[(size_t)t*CONV_DIM];
    float ax = dt*xv;
    #pragma unroll
    for (int q=0;q<16;q++){
      float4 Bq = Bsh[t*16+q];
      hS[4*q+0] = fmaf(dA, hS[4*q+0], ax*Bq.x);
      hS[4*q+1] = fmaf(dA, hS[4*q+1], ax*Bq.y);
      hS[4*q+2] = fmaf(dA, hS[4*q+2], ax*Bq.z);
      hS[4*q+3] = fmaf(dA, hS[4*q+3], ax*Bq.w);
    }
  }
  float4* Sp = (float4*)S + ((((size_t)b*NC + c)*NHEADS + h)*96 + p)*16;
  #pragma unroll
  for (int q=0;q<16;q++)
    Sp[q] = make_float4(hS[4*q],hS[4*q+1],hS[4*q+2],hS[4*q+3]);
}

/* ---------------- pass 2: sequential chunk combine; S becomes Hin (in-place) --- */
__global__ __launch_bounds__(256) void combine_kernel(
    float* __restrict__ S, const float* __restrict__ Dc){
  int g = blockIdx.x*256 + threadIdx.x;     /* (b,h,p,nq): 8*8*96*16 = 98304 */
  int nq = g & 15;
  int p  = (g >> 4) % 96;
  int h  = (g / (16*96)) & 7;
  int b  = g / (16*96*8);
  float4* S4 = (float4*)S;
  const float* Dp = Dc + (size_t)(b*NHEADS + h)*NC;
  float4 H = make_float4(0.f,0.f,0.f,0.f);
  for (int c=0;c<NC;c++){
    size_t base = ((((size_t)b*NC + c)*NHEADS + h)*96 + p)*16 + nq;
    float4 s = S4[base];
    S4[base] = H;                     /* Hin for chunk c = state before chunk c */
    float D = Dp[c];
    H.x = fmaf(D, H.x, s.x);
    H.y = fmaf(D, H.y, s.y);
    H.z = fmaf(D, H.z, s.z);
    H.w = fmaf(D, H.w, s.w);
  }
}

/* ---------------- pass 3: re-scan chunk from Hin, emit y (bf16) ---------------- */
__global__ __launch_bounds__(256) void chunkout_kernel(
    const float* __restrict__ xbc, const float* __restrict__ dtv,
    const float* __restrict__ dAv, const float* __restrict__ Hin,
    const float* __restrict__ D_skip, bf16* __restrict__ y){
  __shared__ float4 Bsh[CHUNK*16];
  __shared__ float4 Csh[CHUNK*16];
  int tid = threadIdx.x;
  int bid = blockIdx.x;
  int part = bid % 3;
  int c = (bid/3) % NC;
  int b = bid / (3*NC);
  int t0 = c*CHUNK;
  for (int i = tid; i < CHUNK*16; i += 256){
    int t = i >> 4, q = i & 15;
    const float4* src = (const float4*)(xbc + ((size_t)(b*SEQ + t0 + t)*CONV_DIM + D_INNER));
    Bsh[i] = src[q];
    Csh[i] = src[q+16];               /* C starts 64 floats (16 float4) after B */
  }
  __syncthreads();
  int u = part*256 + tid;
  int h = u / 96, p = u % 96;
  const float* dtp = dtv + (size_t)(b*NHEADS + h)*SEQ + t0;
  const float* dAp = dAv + (size_t)(b*NHEADS + h)*SEQ + t0;
  const float* xp  = xbc + (size_t)(b*SEQ + t0)*CONV_DIM + h*HEADDIM + p;
  bf16* yp = y + (size_t)(b*SEQ + t0)*D_INNER + h*HEADDIM + p;
  float Dk = D_skip[h];
  float hS[64];
  const float4* Hp = (const float4*)Hin + ((((size_t)b*NC + c)*NHEADS + h)*96 + p)*16;
  #pragma unroll
  for (int q=0;q<16;q++){
    float4 v = Hp[q];
    hS[4*q]=v.x; hS[4*q+1]=v.y; hS[4*q+2]=v.z; hS[4*q+3]=v.w;
  }
  for (int t=0;t<CHUNK;t++){
    float dt = dtp[t], dA = dAp[t];
    float xv = xp[(size_t)t*CONV_DIM];
    float ax = dt*xv;
    float y0=0.f,y1=0.f,y2=0.f,y3=0.f;
    #pragma unroll
    for (int q=0;q<16;q++){
      float4 Bq = Bsh[t*16+q];
      float4 Cq = Csh[t*16+q];
      hS[4*q+0] = fmaf(dA, hS[4*q+0], ax*Bq.x); y0 = fmaf(hS[4*q+0], Cq.x, y0);
      hS[4*q+1] = fmaf(dA, hS[4*q+1], ax*Bq.y); y1 = fmaf(hS[4*q+1], Cq.y, y1);
      hS[4*q+2] = fmaf(dA, hS[4*q+2], ax*Bq.z); y2 = fmaf(hS[4*q+2], Cq.z, y2);
      hS[4*q+3] = fmaf(dA, hS[4*q+3], ax*Bq.w); y3 = fmaf(hS[4*q+3], Cq.w, y3);
    }
    yp[(size_t)t*D_INNER] = __float2bfloat16(fmaf(Dk, xv, (y0+y1)+(y2+y3)));
  }
}

/* ---------------- gate (y * silu(z)) + RMSNorm * norm_w -> bf16 ---------------- */
__global__ void gatenorm_kernel(const bf16* __restrict__ yin, const float* __restrict__ zx,
                                const float* __restrict__ nw, bf16* __restrict__ yout){
  int r = blockIdx.x;
  int tid = threadIdx.x; /* 256 */
  const bf16*  yr = yin + (size_t)r*D_INNER;
  const float* zr = zx  + (size_t)r*D_IN_PROJ;
  float g[3]; float sq = 0.f;
  #pragma unroll
  for (int e=0;e<3;e++){
    int c = tid + 256*e;
    float z = zr[c];
    float v = __bfloat162float(yr[c])*silu_f(z);
    g[e]=v; sq += v*v;
  }
  __shared__ float red[256];
  red[tid]=sq; __syncthreads();
  for (int off=128; off>0; off>>=1){
    if (tid<off) red[tid]+=red[tid+off];
    __syncthreads();
  }
  float rms = rsqrtf(red[0]*(1.f/D_INNER) + 1e-5f);
  bf16* orow = yout + (size_t)r*D_INNER;
  #pragma unroll
  for (int e=0;e<3;e++){
    int c=tid+256*e;
    orow[c]=__float2bfloat16(g[e]*rms*nw[c]);
  }
}

extern "C" void kernel_launch(void* const* d_in, const int* in_sizes, int n_in,
                              void* d_out, int out_size, void* d_ws, size_t ws_size,
                              hipStream_t stream){
  const float* x0      = (const float*)d_in[0];
  const float* ln_w    = (const float*)d_in[1];
  const float* ln_b    = (const float*)d_in[2];
  const float* W_in    = (const float*)d_in[3];
  const float* conv_w  = (const float*)d_in[4];
  const float* conv_b  = (const float*)d_in[5];
  const float* dt_bias = (const float*)d_in[6];
  const float* A_log   = (const float*)d_in[7];
  const float* D_skip  = (const float*)d_in[8];
  const float* norm_w  = (const float*)d_in[9];
  const float* W_out   = (const float*)d_in[10];
  float* out = (float*)d_out;

  /* workspace (float units):
     zx    : 8192*1672            = 13,697,024   fp32
     xbc   : 8192*896             =  7,340,032   fp32
     dtv   : 64*1024              =     65,536
     dAv   : 64*1024              =     65,536
     Dc    : 64*32                =      2,048
     ybuf  : 8192*768 bf16        =  3,145,728 float-units
     Sbuf  : 8*32*8*96*64         = 12,582,912   (hnb/ygb alias here, disjoint lifetime)
     Wt    : 6*1792*384 bf16      =  2,064,384 float-units
     Wot   : 6*384*768 bf16       =    884,736 float-units
     total ~159.4 MB */
  float* zx   = (float*)d_ws;
  float* xbc  = zx   + (size_t)ROWS*D_IN_PROJ;
  float* dtv  = xbc  + (size_t)ROWS*CONV_DIM;
  float* dAv  = dtv  + (size_t)BATCH*NHEADS*SEQ;
  float* Dc   = dAv  + (size_t)BATCH*NHEADS*SEQ;
  bf16*  ybuf = (bf16*)(Dc + (size_t)BATCH*NHEADS*NC);
  float* Sbuf = (float*)(ybuf + (size_t)ROWS*D_INNER);
  bf16*  Wt   = (bf16*)(Sbuf + (size_t)BATCH*NC*NHEADS*HEADDIM*D_STATE);
  bf16*  Wot  = Wt + (size_t)NUM_LAYERS*NPAD_IN*D_MODEL;
  bf16*  hnb  = (bf16*)Sbuf;   /* alias: live ln -> gemm_in, before chunkstate  */
  bf16*  ygb  = (bf16*)Sbuf;   /* alias: live gatenorm -> gemm_out, after scan  */

  hipMemcpyAsync(out, x0, (size_t)ROWS*D_MODEL*sizeof(float),
                 hipMemcpyDeviceToDevice, stream);

  /* one-off per launch: weight transpose+convert to bf16 [N][K] */
  for (int i=0;i<NUM_LAYERS;i++){
    wconv_kernel<<<dim3(NPAD_IN/32, D_MODEL/32), dim3(32,8), 0, stream>>>(
        W_in + (size_t)i*D_MODEL*D_IN_PROJ, Wt + (size_t)i*NPAD_IN*D_MODEL,
        D_MODEL, D_IN_PROJ, NPAD_IN);
    wconv_kernel<<<dim3(NPAD_OUT/32, D_INNER/32), dim3(32,8), 0, stream>>>(
        W_out + (size_t)i*D_INNER*D_MODEL, Wot + (size_t)i*NPAD_OUT*D_INNER,
        D_INNER, D_MODEL, NPAD_OUT);
  }

  for (int i=0;i<NUM_LAYERS;i++){
    ln_kernel<<<ROWS,128,0,stream>>>(out, ln_w+(size_t)i*D_MODEL, ln_b+(size_t)i*D_MODEL, hnb);
    mfma_gemm<0><<<dim3(NPAD_IN/128, ROWS/128), 256, 0, stream>>>(
        (const unsigned short*)hnb, (const unsigned short*)(Wt + (size_t)i*NPAD_IN*D_MODEL),
        zx, D_IN_PROJ, D_MODEL, D_IN_PROJ);
    conv_kernel<<<(ROWS*CONV_DIM)/256, 256, 0, stream>>>(
        zx, conv_w + (size_t)i*CONV_DIM*4, conv_b + (size_t)i*CONV_DIM, xbc);
    dt_kernel<<<(BATCH*NHEADS*SEQ)/256, 256, 0, stream>>>(
        zx, dt_bias+(size_t)i*NHEADS, A_log+(size_t)i*NHEADS, dtv, dAv);
    decay_kernel<<<(BATCH*NHEADS*NC)/256, 256, 0, stream>>>(dAv, Dc);
    chunkstate_kernel<<<BATCH*NC*3, 256, 0, stream>>>(xbc, dtv, dAv, Sbuf);
    combine_kernel<<<(BATCH*NHEADS*96*16)/256, 256, 0, stream>>>(Sbuf, Dc);
    chunkout_kernel<<<BATCH*NC*3, 256, 0, stream>>>(
        xbc, dtv, dAv, Sbuf, D_skip+(size_t)i*NHEADS, ybuf);
    gatenorm_kernel<<<ROWS,256,0,stream>>>(ybuf, zx, norm_w+(size_t)i*D_INNER, ygb);
    mfma_gemm<1><<<dim3(NPAD_OUT/128, ROWS/128), 256, 0, stream>>>(
        (const unsigned short*)ygb, (const unsigned short*)(Wot + (size_t)i*NPAD_OUT*D_INNER),
        out, D_MODEL, D_INNER, D_MODEL);
  }
}

// Round 4
// 1201.405 us; speedup vs baseline: 9.8052x; 1.2506x over previous
//
#include <hip/hip_runtime.h>
#include <hip/hip_bf16.h>
#include <math.h>

#define D_MODEL 384
#define D_STATE 64
#define D_INNER 768
#define HEADDIM 96
#define NHEADS 8
#define CONV_DIM 896
#define D_IN_PROJ 1672
#define BATCH 8
#define SEQ 1024
#define ROWS (BATCH*SEQ)   /* 8192 */
#define NUM_LAYERS 6
#define NC 32              /* chunks */
#define CHUNK 32           /* timesteps per chunk */
#define NPAD_IN 1792       /* 14 * 128 */
#define NPAD_OUT 384       /* 3 * 128  */
#define XP 772             /* padded Xsh row (bf16 elems): 2-way-free banks, 8B-aligned */

typedef __hip_bfloat16 bf16;
using bf16x8_t = __attribute__((ext_vector_type(8))) short;
using f32x4_t  = __attribute__((ext_vector_type(4))) float;

__device__ __forceinline__ float softplus_f(float v){
  return v > 20.f ? v : log1pf(expf(v));
}
__device__ __forceinline__ float silu_f(float v){
  return v / (1.f + expf(-v));
}
__device__ __forceinline__ float bits_to_f(unsigned short u){
  union{unsigned u32; float f;} cv; cv.u32 = ((unsigned)u)<<16; return cv.f;
}
__device__ __forceinline__ unsigned short f_to_bits(float f){
  union{bf16 b; unsigned short u;} cv; cv.b = __float2bfloat16(f); return cv.u;
}

/* ------------- weight transpose + fp32->bf16: W[K][N] -> Wt[Npad][K] ----------- */
__global__ void wconv_kernel(const float* __restrict__ W, bf16* __restrict__ Wt,
                             int K, int N, int Npad){
  __shared__ float tile[32][33];
  int kb = blockIdx.y*32, nb = blockIdx.x*32;
  int tx = threadIdx.x, ty = threadIdx.y;   /* 32 x 8 */
  #pragma unroll
  for (int r=0;r<32;r+=8){
    int k = kb+ty+r, n = nb+tx;
    tile[ty+r][tx] = (k<K && n<N) ? W[(size_t)k*N+n] : 0.f;
  }
  __syncthreads();
  #pragma unroll
  for (int r=0;r<32;r+=8){
    int n = nb+ty+r, k = kb+tx;
    if (n<Npad && k<K) Wt[(size_t)n*K+k] = __float2bfloat16(tile[tx][ty+r]);
  }
}

/* ---------------- LayerNorm: one block (128 thr) per row of 384 -> bf16 -------- */
__global__ void ln_kernel(const float* __restrict__ x, const float* __restrict__ w,
                          const float* __restrict__ b, bf16* __restrict__ o){
  int r = blockIdx.x;
  int tid = threadIdx.x; /* 128 */
  const float* xr = x + (size_t)r*D_MODEL;
  float v[3];
  float s = 0.f, sq = 0.f;
  #pragma unroll
  for (int e=0;e<3;e++){ v[e]=xr[tid+128*e]; s+=v[e]; sq+=v[e]*v[e]; }
  __shared__ float reds[128], redq[128];
  reds[tid]=s; redq[tid]=sq; __syncthreads();
  for (int off=64; off>0; off>>=1){
    if (tid<off){ reds[tid]+=reds[tid+off]; redq[tid]+=redq[tid+off]; }
    __syncthreads();
  }
  float mu = reds[0]*(1.f/D_MODEL);
  float var = redq[0]*(1.f/D_MODEL) - mu*mu;
  var = var < 0.f ? 0.f : var;
  float rstd = rsqrtf(var + 1e-12f);
  bf16* orow = o + (size_t)r*D_MODEL;
  #pragma unroll
  for (int e=0;e<3;e++){
    int c=tid+128*e;
    orow[c] = __float2bfloat16((v[e]-mu)*rstd*w[c] + b[c]);
  }
}

/* ---------------- bf16 MFMA GEMM: C(MxN) = A(MxK) @ Bt(NxK)^T ------------------ */
template<int ACCUM>
__global__ __launch_bounds__(256) void mfma_gemm(
    const unsigned short* __restrict__ A,   /* M x K bf16, row-major */
    const unsigned short* __restrict__ Bt,  /* Npad x K bf16 (B transposed) */
    float* __restrict__ C,                  /* M x ldc fp32 */
    int N, int K, int ldc){
  __shared__ __align__(16) unsigned short As[128*32];
  __shared__ __align__(16) unsigned short Bs[128*32];
  const int tid = threadIdx.x;
  const int wave = tid >> 6, lane = tid & 63;
  const int lq = lane >> 4, lm = lane & 15;
  const int m0 = blockIdx.y * 128, n0 = blockIdx.x * 128;
  const int wm = (wave >> 1) * 64, wn = (wave & 1) * 64;
  f32x4_t acc[4][4];
  #pragma unroll
  for (int i=0;i<4;i++)
    #pragma unroll
    for (int j=0;j<4;j++)
      acc[i][j] = (f32x4_t){0.f,0.f,0.f,0.f};

  for (int k0 = 0; k0 < K; k0 += 32){
    if (k0) __syncthreads();
    #pragma unroll
    for (int q=0;q<2;q++){
      int o = q*4096 + wave*1024 + lane*16;
      int m = o >> 6;
      int kb = o & 63;
      const unsigned short* ga = A  + (size_t)(m0+m)*K + k0 + (kb>>1);
      __builtin_amdgcn_global_load_lds(
          (const __attribute__((address_space(1))) void*)ga,
          (__attribute__((address_space(3))) void*)((char*)As + o), 16, 0, 0);
      const unsigned short* gb = Bt + (size_t)(n0+m)*K + k0 + (kb>>1);
      __builtin_amdgcn_global_load_lds(
          (const __attribute__((address_space(1))) void*)gb,
          (__attribute__((address_space(3))) void*)((char*)Bs + o), 16, 0, 0);
    }
    __syncthreads();
    bf16x8_t af[4], bfv[4];
    #pragma unroll
    for (int i=0;i<4;i++)
      af[i]  = *(const bf16x8_t*)(As + (wm + i*16 + lm)*32 + lq*8);
    #pragma unroll
    for (int j=0;j<4;j++)
      bfv[j] = *(const bf16x8_t*)(Bs + (wn + j*16 + lm)*32 + lq*8);
    #pragma unroll
    for (int i=0;i<4;i++)
      #pragma unroll
      for (int j=0;j<4;j++)
        acc[i][j] = __builtin_amdgcn_mfma_f32_16x16x32_bf16(af[i], bfv[j], acc[i][j], 0, 0, 0);
  }
  #pragma unroll
  for (int i=0;i<4;i++){
    int row = m0 + wm + i*16 + lq*4;
    #pragma unroll
    for (int j=0;j<4;j++){
      int col = n0 + wn + j*16 + lm;
      if (col < N){
        float* cp = C + (size_t)row*ldc + col;
        #pragma unroll
        for (int r=0;r<4;r++){
          if (ACCUM) cp[(size_t)r*ldc] += acc[i][j][r];
          else       cp[(size_t)r*ldc]  = acc[i][j][r];
        }
      }
    }
  }
}

/* ---------------- causal depthwise conv (k=4) + bias + silu -------------------- */
__global__ void conv_kernel(const float* __restrict__ zx, const float* __restrict__ cw,
                            const float* __restrict__ cb, float* __restrict__ o){
  int idx = blockIdx.x*256 + threadIdx.x;
  int c = idx % CONV_DIM;
  int l = (idx / CONV_DIM) % SEQ;
  int b = idx / (CONV_DIM*SEQ);
  const float* src = zx + (size_t)b*SEQ*D_IN_PROJ + D_INNER + c;
  float acc = cb[c];
  #pragma unroll
  for (int j=0;j<4;j++){
    int ls = l - 3 + j;
    if (ls >= 0) acc = fmaf(src[(size_t)ls*D_IN_PROJ], cw[c*4+j], acc);
  }
  o[idx] = silu_f(acc);
}

/* ---------------- precompute dt (softplus) and log-decay = dt*A ---------------- */
__global__ void dt_kernel(const float* __restrict__ zx, const float* __restrict__ dt_bias,
                          const float* __restrict__ A_log,
                          float* __restrict__ dtv, float* __restrict__ ldA){
  int idx = blockIdx.x*256 + threadIdx.x;          /* (b*8+h)*SEQ + t */
  int t = idx & (SEQ-1);
  int h = (idx >> 10) & 7;
  int b = idx >> 13;
  float raw = zx[(size_t)(b*SEQ + t)*D_IN_PROJ + (D_INNER+CONV_DIM) + h];
  float dt = softplus_f(raw + dt_bias[h]);
  float A  = -expf(A_log[h]);
  dtv[idx] = dt;
  ldA[idx] = dt*A;
}

/* ------ pass 1: per (b,chunk) MFMA: G=C.B^T, Y1=(mask*G)@X, S=X^T@(w*B) -------- */
__global__ __launch_bounds__(256) void chunkmm_kernel(
    const float* __restrict__ xbc, const float* __restrict__ dtv,
    const float* __restrict__ ldA, float* __restrict__ cumb,
    float* __restrict__ Dc, unsigned short* __restrict__ Sb,
    unsigned short* __restrict__ y){
  __shared__ __align__(16) unsigned short Xsh[32*XP];   /* X[t][p] bf16 */
  __shared__ __align__(16) unsigned short Bsh[32*72];   /* B[t][n] */
  __shared__ __align__(16) unsigned short Csh[32*72];   /* C[t][n] */
  __shared__ __align__(16) unsigned short BshT[64*40];  /* B[n][t] */
  __shared__ __align__(16) unsigned short Msh[4*32*40]; /* per-wave M~ */
  __shared__ float dtsh[256], Lsh[256], wsh[256];
  const int tid = threadIdx.x;
  const int c = blockIdx.x & 31, b = blockIdx.x >> 5;
  const int t0 = c*CHUNK;
  { /* dt + raw log-decay into LDS */
    int h = tid >> 5, t = tid & 31;
    int gidx = ((b*NHEADS + h) << 10) + t0 + t;
    dtsh[tid] = dtv[gidx];
    Lsh[tid]  = ldA[gidx];
  }
  /* stage X/B/C (fp32 -> bf16) */
  for (int i = tid; i < 32*224; i += 256){
    int t = i/224, q = i%224;
    float4 v = *(const float4*)(xbc + (size_t)(b*SEQ + t0 + t)*CONV_DIM + q*4);
    unsigned short h0=f_to_bits(v.x), h1=f_to_bits(v.y), h2=f_to_bits(v.z), h3=f_to_bits(v.w);
    ushort4 pk = make_ushort4(h0,h1,h2,h3);
    if (q < 192){
      *(ushort4*)&Xsh[t*XP + q*4] = pk;
    } else if (q < 208){
      int n0 = (q-192)*4;
      *(ushort4*)&Bsh[t*72 + n0] = pk;
      BshT[(n0+0)*40 + t] = h0;
      BshT[(n0+1)*40 + t] = h1;
      BshT[(n0+2)*40 + t] = h2;
      BshT[(n0+3)*40 + t] = h3;
    } else {
      int n0 = (q-208)*4;
      *(ushort4*)&Csh[t*72 + n0] = pk;
    }
  }
  __syncthreads();
  if (tid < 8){ /* sequential cumsum per head */
    int h = tid;
    float L = 0.f;
    float* cb = cumb + (size_t)((b*NC + c)*NHEADS + h)*CHUNK;
    for (int t=0;t<32;t++){
      L += Lsh[h*32+t];
      Lsh[h*32+t] = L;
      cb[t] = __expf(L);
    }
    Dc[(b*NHEADS + h)*NC + c] = __expf(L);
    for (int t=0;t<32;t++)
      wsh[h*32+t] = __expf(L - Lsh[h*32+t]) * dtsh[h*32+t];
  }
  __syncthreads();

  const int wave = tid >> 6, lane = tid & 63;
  const int lq = lane >> 4, lm = lane & 15;
  const f32x4_t zero = (f32x4_t){0.f,0.f,0.f,0.f};
  /* G = C.B^T : G[t][s], 2x2 tiles, K=64 */
  f32x4_t G[2][2];
  #pragma unroll
  for (int i=0;i<2;i++){ G[i][0]=zero; G[i][1]=zero; }
  #pragma unroll
  for (int kt=0; kt<2; kt++){
    bf16x8_t ca[2], bb[2];
    #pragma unroll
    for (int ti=0;ti<2;ti++)
      ca[ti] = *(const bf16x8_t*)&Csh[(lm+ti*16)*72 + kt*32 + lq*8];
    #pragma unroll
    for (int si=0;si<2;si++)
      bb[si] = *(const bf16x8_t*)&Bsh[(lm+si*16)*72 + kt*32 + lq*8];
    #pragma unroll
    for (int ti=0;ti<2;ti++)
      #pragma unroll
      for (int si=0;si<2;si++)
        G[ti][si] = __builtin_amdgcn_mfma_f32_16x16x32_bf16(ca[ti], bb[si], G[ti][si], 0,0,0);
  }

  for (int hh=0; hh<2; hh++){
    int h = wave*2 + hh;
    /* M~ = mask .* G .* exp(Lt-Ls) .* dt_s  -> Msh (per-wave) */
    float Lss[2], dts[2];
    #pragma unroll
    for (int si=0;si<2;si++){ Lss[si]=Lsh[h*32+si*16+lm]; dts[si]=dtsh[h*32+si*16+lm]; }
    #pragma unroll
    for (int ti=0;ti<2;ti++){
      #pragma unroll
      for (int r=0;r<4;r++){
        int t = ti*16 + lq*4 + r;
        float Lt = Lsh[h*32 + t];
        #pragma unroll
        for (int si=0;si<2;si++){
          int s = si*16 + lm;
          float m = (s<=t) ? G[ti][si][r]*__expf(Lt - Lss[si])*dts[si] : 0.f;
          Msh[wave*1280 + t*40 + s] = f_to_bits(m);
        }
      }
    }
    __syncthreads();   /* cross-lane Msh visibility (uniform: all waves, 2 iters) */
    bf16x8_t mf[2];
    #pragma unroll
    for (int tt=0;tt<2;tt++)
      mf[tt] = *(const bf16x8_t*)&Msh[wave*1280 + (lm+tt*16)*40 + lq*8];
    /* w-scaled B^T frags for S */
    float wv[8];
    #pragma unroll
    for (int j=0;j<8;j++) wv[j] = wsh[h*32 + lq*8 + j];
    bf16x8_t bw[4];
    #pragma unroll
    for (int nt=0;nt<4;nt++){
      bf16x8_t raw = *(const bf16x8_t*)&BshT[(lm+nt*16)*40 + lq*8];
      #pragma unroll
      for (int j=0;j<8;j++)
        bw[nt][j] = (short)f_to_bits(bits_to_f((unsigned short)raw[j]) * wv[j]);
    }
    const size_t sbase = (size_t)(((b*NC + c)*NHEADS + h))*HEADDIM*D_STATE;
    #pragma unroll
    for (int pt=0; pt<6; pt++){
      int xcol = h*HEADDIM + pt*16 + lm;
      bf16x8_t xf;
      #pragma unroll
      for (int j=0;j<8;j++)
        xf[j] = (short)Xsh[(lq*8+j)*XP + xcol];
      /* Y1 */
      #pragma unroll
      for (int tt=0;tt<2;tt++){
        f32x4_t a = __builtin_amdgcn_mfma_f32_16x16x32_bf16(mf[tt], xf, zero, 0,0,0);
        #pragma unroll
        for (int r=0;r<4;r++){
          int t = tt*16 + lq*4 + r;
          y[(size_t)(b*SEQ + t0 + t)*D_INNER + xcol] = f_to_bits(a[r]);
        }
      }
      /* S */
      #pragma unroll
      for (int nt=0;nt<4;nt++){
        f32x4_t s = __builtin_amdgcn_mfma_f32_16x16x32_bf16(xf, bw[nt], zero, 0,0,0);
        #pragma unroll
        for (int r=0;r<4;r++){
          int p = pt*16 + lq*4 + r;
          Sb[sbase + (size_t)p*D_STATE + nt*16 + lm] = f_to_bits(s[r]);
        }
      }
    }
  }
}

/* ---- pass 2: sequential chunk combine on bf16 S (in-place -> Hin) ------------- */
__global__ __launch_bounds__(256) void combine_kernel(
    unsigned short* __restrict__ S, const float* __restrict__ Dc){
  int g = blockIdx.x*256 + threadIdx.x;     /* (b,h,p,nq): 8*8*96*16 = 98304 */
  int nq = g & 15;
  int p  = (g >> 4) % 96;
  int h  = (g / (16*96)) & 7;
  int b  = g / (16*96*8);
  const float* Dp = Dc + (size_t)(b*NHEADS + h)*NC;
  float H0=0.f,H1=0.f,H2=0.f,H3=0.f;
  for (int c=0;c<NC;c++){
    size_t base = ((((size_t)(b*NC + c)*NHEADS + h)*HEADDIM + p)*D_STATE + nq*4);
    ushort4 s = *(ushort4*)(S + base);
    float s0=bits_to_f(s.x), s1=bits_to_f(s.y), s2=bits_to_f(s.z), s3=bits_to_f(s.w);
    *(ushort4*)(S + base) = make_ushort4(f_to_bits(H0),f_to_bits(H1),f_to_bits(H2),f_to_bits(H3));
    float D = Dp[c];
    H0 = fmaf(D,H0,s0); H1 = fmaf(D,H1,s1); H2 = fmaf(D,H2,s2); H3 = fmaf(D,H3,s3);
  }
}

/* ---- pass 3: y += cum_t * (C @ Hin^T) + D*x  (MFMA) --------------------------- */
__global__ __launch_bounds__(256) void hinadd_kernel(
    const float* __restrict__ xbc, const unsigned short* __restrict__ Hinb,
    const float* __restrict__ cumb, const float* __restrict__ D_skip,
    unsigned short* __restrict__ y){
  __shared__ __align__(16) unsigned short Csh[32*72];
  __shared__ float cumsh[256];
  __shared__ float Dsh[8];
  const int tid = threadIdx.x;
  const int c = blockIdx.x & 31, b = blockIdx.x >> 5;
  const int t0 = c*CHUNK;
  for (int i = tid; i < 32*16; i += 256){
    int t = i>>4, q = i&15;
    float4 v = *(const float4*)(xbc + (size_t)(b*SEQ + t0 + t)*CONV_DIM + (D_INNER + D_STATE) + q*4);
    *(ushort4*)&Csh[t*72 + q*4] =
      make_ushort4(f_to_bits(v.x), f_to_bits(v.y), f_to_bits(v.z), f_to_bits(v.w));
  }
  cumsh[tid] = cumb[(size_t)((b*NC + c)*NHEADS)*CHUNK + tid];   /* h=tid>>5,t=tid&31 */
  if (tid < 8) Dsh[tid] = D_skip[tid];
  __syncthreads();
  const int wave = tid >> 6, lane = tid & 63;
  const int lq = lane >> 4, lm = lane & 15;
  const f32x4_t zero = (f32x4_t){0.f,0.f,0.f,0.f};
  for (int hh=0; hh<2; hh++){
    int h = wave*2 + hh;
    const unsigned short* Hb = Hinb + (size_t)(((b*NC + c)*NHEADS + h))*HEADDIM*D_STATE;
    bf16x8_t ca[2][2];
    #pragma unroll
    for (int tt=0;tt<2;tt++)
      #pragma unroll
      for (int kt=0;kt<2;kt++)
        ca[tt][kt] = *(const bf16x8_t*)&Csh[(lm+tt*16)*72 + kt*32 + lq*8];
    float Dk = Dsh[h];
    #pragma unroll
    for (int pt=0; pt<6; pt++){
      bf16x8_t hf0 = *(const bf16x8_t*)&Hb[(size_t)(lm+pt*16)*D_STATE + lq*8];
      bf16x8_t hf1 = *(const bf16x8_t*)&Hb[(size_t)(lm+pt*16)*D_STATE + 32 + lq*8];
      f32x4_t acc[2];
      #pragma unroll
      for (int tt=0;tt<2;tt++){
        acc[tt] = __builtin_amdgcn_mfma_f32_16x16x32_bf16(ca[tt][0], hf0, zero, 0,0,0);
        acc[tt] = __builtin_amdgcn_mfma_f32_16x16x32_bf16(ca[tt][1], hf1, acc[tt], 0,0,0);
      }
      int pcol = h*HEADDIM + pt*16 + lm;
      #pragma unroll
      for (int tt=0;tt<2;tt++){
        #pragma unroll
        for (int r=0;r<4;r++){
          int t = tt*16 + lq*4 + r;
          float cum = cumsh[h*32 + t];
          size_t row = (size_t)(b*SEQ + t0 + t);
          float xv = xbc[row*CONV_DIM + pcol];
          size_t yo = row*D_INNER + pcol;
          float yv = bits_to_f(y[yo]) + cum*acc[tt][r] + Dk*xv;
          y[yo] = f_to_bits(yv);
        }
      }
    }
  }
}

/* ---------------- gate (y * silu(z)) + RMSNorm * norm_w -> bf16 ---------------- */
__global__ void gatenorm_kernel(const bf16* __restrict__ yin, const float* __restrict__ zx,
                                const float* __restrict__ nw, bf16* __restrict__ yout){
  int r = blockIdx.x;
  int tid = threadIdx.x; /* 256 */
  const bf16*  yr = yin + (size_t)r*D_INNER;
  const float* zr = zx  + (size_t)r*D_IN_PROJ;
  float g[3]; float sq = 0.f;
  #pragma unroll
  for (int e=0;e<3;e++){
    int c = tid + 256*e;
    float z = zr[c];
    float v = __bfloat162float(yr[c])*silu_f(z);
    g[e]=v; sq += v*v;
  }
  __shared__ float red[256];
  red[tid]=sq; __syncthreads();
  for (int off=128; off>0; off>>=1){
    if (tid<off) red[tid]+=red[tid+off];
    __syncthreads();
  }
  float rms = rsqrtf(red[0]*(1.f/D_INNER) + 1e-5f);
  bf16* orow = yout + (size_t)r*D_INNER;
  #pragma unroll
  for (int e=0;e<3;e++){
    int c=tid+256*e;
    orow[c]=__float2bfloat16(g[e]*rms*nw[c]);
  }
}

extern "C" void kernel_launch(void* const* d_in, const int* in_sizes, int n_in,
                              void* d_out, int out_size, void* d_ws, size_t ws_size,
                              hipStream_t stream){
  const float* x0      = (const float*)d_in[0];
  const float* ln_w    = (const float*)d_in[1];
  const float* ln_b    = (const float*)d_in[2];
  const float* W_in    = (const float*)d_in[3];
  const float* conv_w  = (const float*)d_in[4];
  const float* conv_b  = (const float*)d_in[5];
  const float* dt_bias = (const float*)d_in[6];
  const float* A_log   = (const float*)d_in[7];
  const float* D_skip  = (const float*)d_in[8];
  const float* norm_w  = (const float*)d_in[9];
  const float* W_out   = (const float*)d_in[10];
  float* out = (float*)d_out;

  /* workspace (float units), total ~134.5 MB:
     zx 13,697,024 | xbc 7,340,032 | dtv 65,536 | ldA 65,536 | cumb 65,536
     Dc 2,048 | ybuf(bf16) 3,145,728 | Sb(bf16, also Hin + hnb/ygb alias) 6,291,456
     Wt(bf16) 2,064,384 | Wot(bf16) 884,736 */
  float* p    = (float*)d_ws;
  float* zx   = p;  p += (size_t)ROWS*D_IN_PROJ;
  float* xbc  = p;  p += (size_t)ROWS*CONV_DIM;
  float* dtv  = p;  p += (size_t)BATCH*NHEADS*SEQ;
  float* ldA  = p;  p += (size_t)BATCH*NHEADS*SEQ;
  float* cumb = p;  p += (size_t)BATCH*NHEADS*SEQ;
  float* Dc   = p;  p += (size_t)BATCH*NHEADS*NC;
  unsigned short* ybuf = (unsigned short*)p;  p += (size_t)ROWS*D_INNER/2;
  unsigned short* Sb   = (unsigned short*)p;  p += (size_t)BATCH*NC*NHEADS*HEADDIM*D_STATE/2;
  bf16* Wt  = (bf16*)p; p += (size_t)NUM_LAYERS*NPAD_IN*D_MODEL/2;
  bf16* Wot = (bf16*)p;
  bf16* hnb = (bf16*)Sb;   /* alias: live ln -> gemm_in, dead before chunkmm   */
  bf16* ygb = (bf16*)Sb;   /* alias: live gatenorm -> gemm_out, after hinadd   */

  hipMemcpyAsync(out, x0, (size_t)ROWS*D_MODEL*sizeof(float),
                 hipMemcpyDeviceToDevice, stream);

  for (int i=0;i<NUM_LAYERS;i++){
    wconv_kernel<<<dim3(NPAD_IN/32, D_MODEL/32), dim3(32,8), 0, stream>>>(
        W_in + (size_t)i*D_MODEL*D_IN_PROJ, Wt + (size_t)i*NPAD_IN*D_MODEL,
        D_MODEL, D_IN_PROJ, NPAD_IN);
    wconv_kernel<<<dim3(NPAD_OUT/32, D_INNER/32), dim3(32,8), 0, stream>>>(
        W_out + (size_t)i*D_INNER*D_MODEL, Wot + (size_t)i*NPAD_OUT*D_INNER,
        D_INNER, D_MODEL, NPAD_OUT);
  }

  for (int i=0;i<NUM_LAYERS;i++){
    ln_kernel<<<ROWS,128,0,stream>>>(out, ln_w+(size_t)i*D_MODEL, ln_b+(size_t)i*D_MODEL, hnb);
    mfma_gemm<0><<<dim3(NPAD_IN/128, ROWS/128), 256, 0, stream>>>(
        (const unsigned short*)hnb, (const unsigned short*)(Wt + (size_t)i*NPAD_IN*D_MODEL),
        zx, D_IN_PROJ, D_MODEL, D_IN_PROJ);
    conv_kernel<<<(ROWS*CONV_DIM)/256, 256, 0, stream>>>(
        zx, conv_w + (size_t)i*CONV_DIM*4, conv_b + (size_t)i*CONV_DIM, xbc);
    dt_kernel<<<(BATCH*NHEADS*SEQ)/256, 256, 0, stream>>>(
        zx, dt_bias+(size_t)i*NHEADS, A_log+(size_t)i*NHEADS, dtv, ldA);
    chunkmm_kernel<<<BATCH*NC, 256, 0, stream>>>(
        xbc, dtv, ldA, cumb, Dc, Sb, ybuf);
    combine_kernel<<<(BATCH*NHEADS*HEADDIM*16)/256, 256, 0, stream>>>(Sb, Dc);
    hinadd_kernel<<<BATCH*NC, 256, 0, stream>>>(
        xbc, Sb, cumb, D_skip+(size_t)i*NHEADS, ybuf);
    gatenorm_kernel<<<ROWS,256,0,stream>>>((const bf16*)ybuf, zx, norm_w+(size_t)i*D_INNER, ygb);
    mfma_gemm<1><<<dim3(NPAD_OUT/128, ROWS/128), 256, 0, stream>>>(
        (const unsigned short*)ygb, (const unsigned short*)(Wot + (size_t)i*NPAD_OUT*D_INNER),
        out, D_MODEL, D_INNER, D_MODEL);
  }
}

// Round 5
// 961.456 us; speedup vs baseline: 12.2522x; 1.2496x over previous
//
#include <hip/hip_runtime.h>
#include <hip/hip_bf16.h>
#include <math.h>

#define D_MODEL 384
#define D_STATE 64
#define D_INNER 768
#define HEADDIM 96
#define NHEADS 8
#define CONV_DIM 896
#define D_IN_PROJ 1672
#define BATCH 8
#define SEQ 1024
#define ROWS (BATCH*SEQ)   /* 8192 */
#define NUM_LAYERS 6
#define NC 32              /* chunks */
#define CHUNK 32           /* timesteps per chunk */
#define NPAD_IN 1792       /* 14 * 128 */
#define NPAD_OUT 384       /* 3 * 128  */

typedef __hip_bfloat16 bf16;
using bf16x8_t = __attribute__((ext_vector_type(8))) short;
using f32x4_t  = __attribute__((ext_vector_type(4))) float;

__device__ __forceinline__ float softplus_f(float v){
  return v > 20.f ? v : log1pf(expf(v));
}
__device__ __forceinline__ float silu_f(float v){
  return v / (1.f + expf(-v));
}
__device__ __forceinline__ float bits_to_f(unsigned short u){
  union{unsigned u32; float f;} cv; cv.u32 = ((unsigned)u)<<16; return cv.f;
}
__device__ __forceinline__ unsigned short f_to_bits(float f){
  union{bf16 b; unsigned short u;} cv; cv.b = __float2bfloat16(f); return cv.u;
}

/* ------------- weight transpose + fp32->bf16: W[K][N] -> Wt[Npad][K] ----------- */
__global__ void wconv_kernel(const float* __restrict__ W, bf16* __restrict__ Wt,
                             int K, int N, int Npad){
  __shared__ float tile[32][33];
  int kb = blockIdx.y*32, nb = blockIdx.x*32;
  int tx = threadIdx.x, ty = threadIdx.y;   /* 32 x 8 */
  #pragma unroll
  for (int r=0;r<32;r+=8){
    int k = kb+ty+r, n = nb+tx;
    tile[ty+r][tx] = (k<K && n<N) ? W[(size_t)k*N+n] : 0.f;
  }
  __syncthreads();
  #pragma unroll
  for (int r=0;r<32;r+=8){
    int n = nb+ty+r, k = kb+tx;
    if (n<Npad && k<K) Wt[(size_t)n*K+k] = __float2bfloat16(tile[tx][ty+r]);
  }
}

/* ---------------- LayerNorm: one block (128 thr) per row of 384 -> bf16 -------- */
__global__ void ln_kernel(const float* __restrict__ x, const float* __restrict__ w,
                          const float* __restrict__ b, bf16* __restrict__ o){
  int r = blockIdx.x;
  int tid = threadIdx.x; /* 128 */
  const float* xr = x + (size_t)r*D_MODEL;
  float v[3];
  float s = 0.f, sq = 0.f;
  #pragma unroll
  for (int e=0;e<3;e++){ v[e]=xr[tid+128*e]; s+=v[e]; sq+=v[e]*v[e]; }
  __shared__ float reds[128], redq[128];
  reds[tid]=s; redq[tid]=sq; __syncthreads();
  for (int off=64; off>0; off>>=1){
    if (tid<off){ reds[tid]+=reds[tid+off]; redq[tid]+=redq[tid+off]; }
    __syncthreads();
  }
  float mu = reds[0]*(1.f/D_MODEL);
  float var = redq[0]*(1.f/D_MODEL) - mu*mu;
  var = var < 0.f ? 0.f : var;
  float rstd = rsqrtf(var + 1e-12f);
  bf16* orow = o + (size_t)r*D_MODEL;
  #pragma unroll
  for (int e=0;e<3;e++){
    int c=tid+128*e;
    orow[c] = __float2bfloat16((v[e]-mu)*rstd*w[c] + b[c]);
  }
}

/* ---------------- bf16 MFMA GEMM: C(MxN) = A(MxK) @ Bt(NxK)^T ------------------ */
template<int ACCUM>
__global__ __launch_bounds__(256) void mfma_gemm(
    const unsigned short* __restrict__ A,   /* M x K bf16, row-major */
    const unsigned short* __restrict__ Bt,  /* Npad x K bf16 (B transposed) */
    float* __restrict__ C,                  /* M x ldc fp32 */
    int N, int K, int ldc){
  __shared__ __align__(16) unsigned short As[128*32];
  __shared__ __align__(16) unsigned short Bs[128*32];
  const int tid = threadIdx.x;
  const int wave = tid >> 6, lane = tid & 63;
  const int lq = lane >> 4, lm = lane & 15;
  const int m0 = blockIdx.y * 128, n0 = blockIdx.x * 128;
  const int wm = (wave >> 1) * 64, wn = (wave & 1) * 64;
  f32x4_t acc[4][4];
  #pragma unroll
  for (int i=0;i<4;i++)
    #pragma unroll
    for (int j=0;j<4;j++)
      acc[i][j] = (f32x4_t){0.f,0.f,0.f,0.f};

  for (int k0 = 0; k0 < K; k0 += 32){
    if (k0) __syncthreads();
    #pragma unroll
    for (int q=0;q<2;q++){
      int o = q*4096 + wave*1024 + lane*16;
      int m = o >> 6;
      int kb = o & 63;
      const unsigned short* ga = A  + (size_t)(m0+m)*K + k0 + (kb>>1);
      __builtin_amdgcn_global_load_lds(
          (const __attribute__((address_space(1))) void*)ga,
          (__attribute__((address_space(3))) void*)((char*)As + o), 16, 0, 0);
      const unsigned short* gb = Bt + (size_t)(n0+m)*K + k0 + (kb>>1);
      __builtin_amdgcn_global_load_lds(
          (const __attribute__((address_space(1))) void*)gb,
          (__attribute__((address_space(3))) void*)((char*)Bs + o), 16, 0, 0);
    }
    __syncthreads();
    bf16x8_t af[4], bfv[4];
    #pragma unroll
    for (int i=0;i<4;i++)
      af[i]  = *(const bf16x8_t*)(As + (wm + i*16 + lm)*32 + lq*8);
    #pragma unroll
    for (int j=0;j<4;j++)
      bfv[j] = *(const bf16x8_t*)(Bs + (wn + j*16 + lm)*32 + lq*8);
    #pragma unroll
    for (int i=0;i<4;i++)
      #pragma unroll
      for (int j=0;j<4;j++)
        acc[i][j] = __builtin_amdgcn_mfma_f32_16x16x32_bf16(af[i], bfv[j], acc[i][j], 0, 0, 0);
  }
  #pragma unroll
  for (int i=0;i<4;i++){
    int row = m0 + wm + i*16 + lq*4;
    #pragma unroll
    for (int j=0;j<4;j++){
      int col = n0 + wn + j*16 + lm;
      if (col < N){
        float* cp = C + (size_t)row*ldc + col;
        #pragma unroll
        for (int r=0;r<4;r++){
          if (ACCUM) cp[(size_t)r*ldc] += acc[i][j][r];
          else       cp[(size_t)r*ldc]  = acc[i][j][r];
        }
      }
    }
  }
}

/* ==== fused conv(k=4)+silu + dt/softplus + cumsum + chunked-SSD matmuls ========
   grid: BATCH*NC*4 blocks; block handles (b, chunk c, head-pair hp={2h,2h+1}).
   Outputs: y (Y1 + D*x via M-diagonal), Sb (chunk states), cumb, Dc, Cb.     */
__global__ __launch_bounds__(256) void fused_scan_kernel(
    const float* __restrict__ zx, const float* __restrict__ cw,
    const float* __restrict__ cb, const float* __restrict__ dt_bias,
    const float* __restrict__ A_log, const float* __restrict__ D_skip,
    float* __restrict__ cumb, float* __restrict__ Dc,
    unsigned short* __restrict__ Cb, unsigned short* __restrict__ Sb,
    unsigned short* __restrict__ y){
  __shared__ __align__(16) unsigned short XshT[192*40];  /* X^T[p_local][t] */
  __shared__ __align__(16) unsigned short BshT[64*40];   /* B^T[n][t] */
  __shared__ __align__(16) unsigned short Bsh[32*72];    /* B[t][n] */
  __shared__ __align__(16) unsigned short Csh[32*72];    /* C[t][n] */
  __shared__ __align__(16) unsigned short Msh[2*32*40];  /* M~ per head */
  __shared__ float dtsh[64], Lsh[64], wsh[64];
  const int tid = threadIdx.x;
  const int bid = blockIdx.x;
  const int hp = bid & 3, c = (bid >> 2) & 31, b = bid >> 7;
  const int h_base = hp*2;
  const int t0 = c*CHUNK;

  /* ---- dt + raw log-decay for this block's 2 heads ---- */
  if (tid < 64){
    int hi = tid >> 5, t = tid & 31;
    int hg = h_base + hi;
    float raw = zx[(size_t)(b*SEQ + t0 + t)*D_IN_PROJ + (D_INNER+CONV_DIM) + hg];
    float dtv_ = softplus_f(raw + dt_bias[hg]);
    dtsh[tid] = dtv_;
    Lsh[tid]  = dtv_ * (-expf(A_log[hg]));
  }

  /* ---- conv: thread-per-column, rolling 4-tap window, silu -> LDS ---- */
  #pragma unroll
  for (int it=0; it<2; it++){
    int ci = it*256 + tid;
    if (ci < 320){
      int gcol;             /* column in zx */
      if (ci < 192) gcol = D_INNER + (h_base + ci/96)*HEADDIM + (ci%96);
      else          gcol = D_INNER + D_INNER + (ci - 192);   /* B/C: 1536.. */
      int cch = gcol - D_INNER;                              /* conv channel */
      float4 w4 = *(const float4*)(cw + cch*4);
      float bias = cb[cch];
      const float* src = zx + (size_t)b*SEQ*D_IN_PROJ + gcol;
      float v0=0.f,v1=0.f,v2=0.f,v3=0.f;
      unsigned prev = 0;
      for (int t=-3; t<32; t++){
        int l = t0 + t;
        float nv = (l >= 0) ? src[(size_t)l*D_IN_PROJ] : 0.f;
        v0=v1; v1=v2; v2=v3; v3=nv;
        if (t < 0) continue;
        float a = silu_f(bias + w4.x*v0 + w4.y*v1 + w4.z*v2 + w4.w*v3);
        unsigned short ub = f_to_bits(a);
        if (ci < 192){
          if (t & 1) *(unsigned*)&XshT[ci*40 + (t-1)] = prev | ((unsigned)ub<<16);
          else prev = ub;
        } else if (cch < CONV_DIM - D_STATE){      /* B: cch 768..831 */
          int n = cch - D_INNER;
          Bsh[t*72 + n] = ub;
          if (t & 1) *(unsigned*)&BshT[n*40 + (t-1)] = prev | ((unsigned)ub<<16);
          else prev = ub;
        } else {                                    /* C: cch 832..895 */
          Csh[t*72 + (cch - D_INNER - D_STATE)] = ub;
        }
      }
    }
  }
  __syncthreads();

  /* ---- sequential cumsum of log-decay; chunk decay products; w-scale ---- */
  if (tid < 2){
    int hg = h_base + tid;
    float L = 0.f;
    float* cbp = cumb + ((size_t)((b*NC + c)*NHEADS) + hg)*CHUNK;
    for (int t=0;t<32;t++){
      L += Lsh[tid*32+t];
      Lsh[tid*32+t] = L;
      cbp[t] = __expf(L);
    }
    Dc[(b*NHEADS + hg)*NC + c] = __expf(L);
    for (int t=0;t<32;t++)
      wsh[tid*32+t] = __expf(L - Lsh[tid*32+t]) * dtsh[tid*32+t];
  }
  __syncthreads();

  const int wave = tid >> 6, lane = tid & 63;
  const int lq = lane >> 4, lm = lane & 15;
  const f32x4_t zero = (f32x4_t){0.f,0.f,0.f,0.f};

  /* ---- waves 0,1: G = C.B^T then M~ (with D-skip on diagonal); waves 2,3: Cb out */
  if (wave < 2){
    f32x4_t G[2][2];
    #pragma unroll
    for (int i=0;i<2;i++){ G[i][0]=zero; G[i][1]=zero; }
    #pragma unroll
    for (int kt=0; kt<2; kt++){
      bf16x8_t ca[2], bb[2];
      #pragma unroll
      for (int ti=0;ti<2;ti++)
        ca[ti] = *(const bf16x8_t*)&Csh[(lm+ti*16)*72 + kt*32 + lq*8];
      #pragma unroll
      for (int si=0;si<2;si++)
        bb[si] = *(const bf16x8_t*)&Bsh[(lm+si*16)*72 + kt*32 + lq*8];
      #pragma unroll
      for (int ti=0;ti<2;ti++)
        #pragma unroll
        for (int si=0;si<2;si++)
          G[ti][si] = __builtin_amdgcn_mfma_f32_16x16x32_bf16(ca[ti], bb[si], G[ti][si], 0,0,0);
    }
    int hi = wave;
    float Dk = D_skip[h_base + hi];
    float Lss[2], dts[2];
    #pragma unroll
    for (int si=0;si<2;si++){ Lss[si]=Lsh[hi*32+si*16+lm]; dts[si]=dtsh[hi*32+si*16+lm]; }
    #pragma unroll
    for (int ti=0;ti<2;ti++){
      #pragma unroll
      for (int r=0;r<4;r++){
        int t = ti*16 + lq*4 + r;
        float Lt = Lsh[hi*32 + t];
        #pragma unroll
        for (int si=0;si<2;si++){
          int s = si*16 + lm;
          float m = 0.f;
          if (s <= t){
            m = G[ti][si][r]*__expf(Lt - Lss[si])*dts[si];
            if (s == t) m += Dk;
          }
          Msh[hi*1280 + t*40 + s] = f_to_bits(m);
        }
      }
    }
  } else if (hp == 0){
    int lt = tid - 128;
    for (int i = lt; i < 512; i += 128){
      int t = i >> 4, q = i & 15;
      *(ushort4*)(Cb + ((size_t)(b*SEQ) + t0 + t)*D_STATE + q*4) =
          *(const ushort4*)&Csh[t*72 + q*4];
    }
  }
  __syncthreads();

  /* ---- compute: wave -> (head hi = wave&1, pt-half = wave>>1) ---- */
  {
    int hi = wave & 1, hg = h_base + hi;
    int ptb = (wave >> 1)*3;
    bf16x8_t mf[2];
    #pragma unroll
    for (int tt=0;tt<2;tt++)
      mf[tt] = *(const bf16x8_t*)&Msh[hi*1280 + (lm+tt*16)*40 + lq*8];
    float wv[8];
    #pragma unroll
    for (int j=0;j<8;j++) wv[j] = wsh[hi*32 + lq*8 + j];
    bf16x8_t bw[4];
    #pragma unroll
    for (int nt=0;nt<4;nt++){
      bf16x8_t raw = *(const bf16x8_t*)&BshT[(lm+nt*16)*40 + lq*8];
      #pragma unroll
      for (int j=0;j<8;j++)
        bw[nt][j] = (short)f_to_bits(bits_to_f((unsigned short)raw[j]) * wv[j]);
    }
    const size_t sbase = ((size_t)((b*NC + c)*NHEADS) + hg)*HEADDIM*D_STATE;
    #pragma unroll
    for (int pp=0; pp<3; pp++){
      int pt = ptb + pp;
      bf16x8_t xf = *(const bf16x8_t*)&XshT[(hi*96 + pt*16 + lm)*40 + lq*8];
      /* Y1 (+ D*x via diagonal) */
      #pragma unroll
      for (int tt=0;tt<2;tt++){
        f32x4_t a = __builtin_amdgcn_mfma_f32_16x16x32_bf16(mf[tt], xf, zero, 0,0,0);
        #pragma unroll
        for (int r=0;r<4;r++){
          int t = tt*16 + lq*4 + r;
          y[((size_t)(b*SEQ) + t0 + t)*D_INNER + hg*HEADDIM + pt*16 + lm] = f_to_bits(a[r]);
        }
      }
      /* S = X^T @ (w.B) */
      #pragma unroll
      for (int nt=0;nt<4;nt++){
        f32x4_t s = __builtin_amdgcn_mfma_f32_16x16x32_bf16(xf, bw[nt], zero, 0,0,0);
        #pragma unroll
        for (int r=0;r<4;r++){
          int p = pt*16 + lq*4 + r;
          Sb[sbase + (size_t)p*D_STATE + nt*16 + lm] = f_to_bits(s[r]);
        }
      }
    }
  }
}

/* ---- sequential chunk combine on bf16 S (in-place -> Hin) --------------------- */
__global__ __launch_bounds__(256) void combine_kernel(
    unsigned short* __restrict__ S, const float* __restrict__ Dc){
  int g = blockIdx.x*256 + threadIdx.x;     /* (b,h,p,nq): 8*8*96*16 = 98304 */
  int nq = g & 15;
  int p  = (g >> 4) % 96;
  int h  = (g / (16*96)) & 7;
  int b  = g / (16*96*8);
  const float* Dp = Dc + (size_t)(b*NHEADS + h)*NC;
  float H0=0.f,H1=0.f,H2=0.f,H3=0.f;
  for (int c=0;c<NC;c++){
    size_t base = ((((size_t)(b*NC + c)*NHEADS + h)*HEADDIM + p)*D_STATE + nq*4);
    ushort4 s = *(ushort4*)(S + base);
    float s0=bits_to_f(s.x), s1=bits_to_f(s.y), s2=bits_to_f(s.z), s3=bits_to_f(s.w);
    *(ushort4*)(S + base) = make_ushort4(f_to_bits(H0),f_to_bits(H1),f_to_bits(H2),f_to_bits(H3));
    float D = Dp[c];
    H0 = fmaf(D,H0,s0); H1 = fmaf(D,H1,s1); H2 = fmaf(D,H2,s2); H3 = fmaf(D,H3,s3);
  }
}

/* ---- y += cum_t * (C @ Hin^T)  (MFMA, C/Hin from global bf16) ----------------- */
__global__ __launch_bounds__(256) void hinadd_kernel(
    const unsigned short* __restrict__ Cb, const unsigned short* __restrict__ Hinb,
    const float* __restrict__ cumb, unsigned short* __restrict__ y){
  __shared__ float cumsh[256];
  const int tid = threadIdx.x;
  const int c = blockIdx.x & 31, b = blockIdx.x >> 5;
  const int t0 = c*CHUNK;
  cumsh[tid] = cumb[(size_t)((b*NC + c)*NHEADS)*CHUNK + tid];   /* h=tid>>5,t=tid&31 */
  __syncthreads();
  const int wave = tid >> 6, lane = tid & 63;
  const int lq = lane >> 4, lm = lane & 15;
  const f32x4_t zero = (f32x4_t){0.f,0.f,0.f,0.f};
  for (int hh=0; hh<2; hh++){
    int h = wave*2 + hh;
    const unsigned short* Hb = Hinb + ((size_t)((b*NC + c)*NHEADS) + h)*HEADDIM*D_STATE;
    bf16x8_t ca[2][2];
    #pragma unroll
    for (int tt=0;tt<2;tt++)
      #pragma unroll
      for (int kt=0;kt<2;kt++)
        ca[tt][kt] = *(const bf16x8_t*)(Cb +
            ((size_t)(b*SEQ) + t0 + tt*16 + lm)*D_STATE + kt*32 + lq*8);
    #pragma unroll
    for (int pt=0; pt<6; pt++){
      bf16x8_t hf0 = *(const bf16x8_t*)&Hb[(size_t)(lm+pt*16)*D_STATE + lq*8];
      bf16x8_t hf1 = *(const bf16x8_t*)&Hb[(size_t)(lm+pt*16)*D_STATE + 32 + lq*8];
      f32x4_t acc[2];
      #pragma unroll
      for (int tt=0;tt<2;tt++){
        acc[tt] = __builtin_amdgcn_mfma_f32_16x16x32_bf16(ca[tt][0], hf0, zero, 0,0,0);
        acc[tt] = __builtin_amdgcn_mfma_f32_16x16x32_bf16(ca[tt][1], hf1, acc[tt], 0,0,0);
      }
      int pcol = h*HEADDIM + pt*16 + lm;
      #pragma unroll
      for (int tt=0;tt<2;tt++){
        #pragma unroll
        for (int r=0;r<4;r++){
          int t = tt*16 + lq*4 + r;
          float cum = cumsh[h*32 + t];
          size_t yo = ((size_t)(b*SEQ) + t0 + t)*D_INNER + pcol;
          y[yo] = f_to_bits(bits_to_f(y[yo]) + cum*acc[tt][r]);
        }
      }
    }
  }
}

/* ---------------- gate (y * silu(z)) + RMSNorm * norm_w -> bf16 ---------------- */
__global__ void gatenorm_kernel(const bf16* __restrict__ yin, const float* __restrict__ zx,
                                const float* __restrict__ nw, bf16* __restrict__ yout){
  int r = blockIdx.x;
  int tid = threadIdx.x; /* 256 */
  const bf16*  yr = yin + (size_t)r*D_INNER;
  const float* zr = zx  + (size_t)r*D_IN_PROJ;
  float g[3]; float sq = 0.f;
  #pragma unroll
  for (int e=0;e<3;e++){
    int c = tid + 256*e;
    float z = zr[c];
    float v = __bfloat162float(yr[c])*silu_f(z);
    g[e]=v; sq += v*v;
  }
  __shared__ float red[256];
  red[tid]=sq; __syncthreads();
  for (int off=128; off>0; off>>=1){
    if (tid<off) red[tid]+=red[tid+off];
    __syncthreads();
  }
  float rms = rsqrtf(red[0]*(1.f/D_INNER) + 1e-5f);
  bf16* orow = yout + (size_t)r*D_INNER;
  #pragma unroll
  for (int e=0;e<3;e++){
    int c=tid+256*e;
    orow[c]=__float2bfloat16(g[e]*rms*nw[c]);
  }
}

extern "C" void kernel_launch(void* const* d_in, const int* in_sizes, int n_in,
                              void* d_out, int out_size, void* d_ws, size_t ws_size,
                              hipStream_t stream){
  const float* x0      = (const float*)d_in[0];
  const float* ln_w    = (const float*)d_in[1];
  const float* ln_b    = (const float*)d_in[2];
  const float* W_in    = (const float*)d_in[3];
  const float* conv_w  = (const float*)d_in[4];
  const float* conv_b  = (const float*)d_in[5];
  const float* dt_bias = (const float*)d_in[6];
  const float* A_log   = (const float*)d_in[7];
  const float* D_skip  = (const float*)d_in[8];
  const float* norm_w  = (const float*)d_in[9];
  const float* W_out   = (const float*)d_in[10];
  float* out = (float*)d_out;

  /* workspace (float units), ~87 MB:
     zx 13,697,024 | cumb 65,536 | Dc 2,048 | ybuf(bf16) 3,145,728fl
     Sb(bf16, also Hin + hnb/ygb alias) 6,291,456fl | Cb(bf16) 262,144fl
     Wt(bf16) 2,064,384fl | Wot(bf16) 884,736fl */
  float* p    = (float*)d_ws;
  float* zx   = p;  p += (size_t)ROWS*D_IN_PROJ;
  float* cumb = p;  p += (size_t)BATCH*NHEADS*SEQ;
  float* Dc   = p;  p += (size_t)BATCH*NHEADS*NC;
  unsigned short* ybuf = (unsigned short*)p;  p += (size_t)ROWS*D_INNER/2;
  unsigned short* Sb   = (unsigned short*)p;  p += (size_t)BATCH*NC*NHEADS*HEADDIM*D_STATE/2;
  unsigned short* Cb   = (unsigned short*)p;  p += (size_t)ROWS*D_STATE/2;
  bf16* Wt  = (bf16*)p; p += (size_t)NUM_LAYERS*NPAD_IN*D_MODEL/2;
  bf16* Wot = (bf16*)p;
  bf16* hnb = (bf16*)Sb;   /* alias: live ln -> gemm_in, dead before fused_scan */
  bf16* ygb = (bf16*)Sb;   /* alias: live gatenorm -> gemm_out, after hinadd    */

  hipMemcpyAsync(out, x0, (size_t)ROWS*D_MODEL*sizeof(float),
                 hipMemcpyDeviceToDevice, stream);

  for (int i=0;i<NUM_LAYERS;i++){
    wconv_kernel<<<dim3(NPAD_IN/32, D_MODEL/32), dim3(32,8), 0, stream>>>(
        W_in + (size_t)i*D_MODEL*D_IN_PROJ, Wt + (size_t)i*NPAD_IN*D_MODEL,
        D_MODEL, D_IN_PROJ, NPAD_IN);
    wconv_kernel<<<dim3(NPAD_OUT/32, D_INNER/32), dim3(32,8), 0, stream>>>(
        W_out + (size_t)i*D_INNER*D_MODEL, Wot + (size_t)i*NPAD_OUT*D_INNER,
        D_INNER, D_MODEL, NPAD_OUT);
  }

  for (int i=0;i<NUM_LAYERS;i++){
    ln_kernel<<<ROWS,128,0,stream>>>(out, ln_w+(size_t)i*D_MODEL, ln_b+(size_t)i*D_MODEL, hnb);
    mfma_gemm<0><<<dim3(NPAD_IN/128, ROWS/128), 256, 0, stream>>>(
        (const unsigned short*)hnb, (const unsigned short*)(Wt + (size_t)i*NPAD_IN*D_MODEL),
        zx, D_IN_PROJ, D_MODEL, D_IN_PROJ);
    fused_scan_kernel<<<BATCH*NC*4, 256, 0, stream>>>(
        zx, conv_w + (size_t)i*CONV_DIM*4, conv_b + (size_t)i*CONV_DIM,
        dt_bias+(size_t)i*NHEADS, A_log+(size_t)i*NHEADS, D_skip+(size_t)i*NHEADS,
        cumb, Dc, Cb, Sb, ybuf);
    combine_kernel<<<(BATCH*NHEADS*HEADDIM*16)/256, 256, 0, stream>>>(Sb, Dc);
    hinadd_kernel<<<BATCH*NC, 256, 0, stream>>>(Cb, Sb, cumb, ybuf);
    gatenorm_kernel<<<ROWS,256,0,stream>>>((const bf16*)ybuf, zx, norm_w+(size_t)i*D_INNER, ygb);
    mfma_gemm<1><<<dim3(NPAD_OUT/128, ROWS/128), 256, 0, stream>>>(
        (const unsigned short*)ygb, (const unsigned short*)(Wot + (size_t)i*NPAD_OUT*D_INNER),
        out, D_MODEL, D_INNER, D_MODEL);
  }
}

// Round 6
// 849.189 us; speedup vs baseline: 13.8720x; 1.1322x over previous
//
#include <hip/hip_runtime.h>
#include <hip/hip_bf16.h>
#include <math.h>

#define D_MODEL 384
#define D_STATE 64
#define D_INNER 768
#define HEADDIM 96
#define NHEADS 8
#define CONV_DIM 896
#define D_IN_PROJ 1672
#define ZXB_LD 1664        /* bf16 zx row stride (z,X,B,C); dt split to fp32 */
#define BATCH 8
#define SEQ 1024
#define ROWS (BATCH*SEQ)   /* 8192 */
#define NUM_LAYERS 6
#define NC 32              /* chunks */
#define CHUNK 32           /* timesteps per chunk */
#define NPAD_IN 1792       /* 14 * 128 */
#define NPAD_OUT 384       /* 3 * 128  */
#define VP 776             /* padded Vsh row (shorts): 8-bank offset per 4 rows */

typedef __hip_bfloat16 bf16;
using bf16x8_t = __attribute__((ext_vector_type(8))) short;
using f32x4_t  = __attribute__((ext_vector_type(4))) float;

__device__ __forceinline__ float softplus_f(float v){
  return v > 20.f ? v : log1pf(expf(v));
}
__device__ __forceinline__ float silu_f(float v){
  return v / (1.f + expf(-v));
}
__device__ __forceinline__ float bits_to_f(unsigned short u){
  union{unsigned u32; float f;} cv; cv.u32 = ((unsigned)u)<<16; return cv.f;
}
__device__ __forceinline__ unsigned short f_to_bits(float f){
  union{bf16 b; unsigned short u;} cv; cv.b = __float2bfloat16(f); return cv.u;
}

/* ------- weight transpose + fp32->bf16, all layers batched via grid.z ---------- */
__global__ void wconv_kernel(const float* __restrict__ W, bf16* __restrict__ Wt,
                             int K, int N, int Npad){
  __shared__ float tile[32][33];
  W  += (size_t)blockIdx.z*K*N;
  Wt += (size_t)blockIdx.z*Npad*K;
  int kb = blockIdx.y*32, nb = blockIdx.x*32;
  int tx = threadIdx.x, ty = threadIdx.y;   /* 32 x 8 */
  #pragma unroll
  for (int r=0;r<32;r+=8){
    int k = kb+ty+r, n = nb+tx;
    tile[ty+r][tx] = (k<K && n<N) ? W[(size_t)k*N+n] : 0.f;
  }
  __syncthreads();
  #pragma unroll
  for (int r=0;r<32;r+=8){
    int n = nb+ty+r, k = kb+tx;
    if (n<Npad && k<K) Wt[(size_t)n*K+k] = __float2bfloat16(tile[tx][ty+r]);
  }
}

/* ---------------- LayerNorm: one block (128 thr) per row of 384 -> bf16 -------- */
__global__ void ln_kernel(const float* __restrict__ x, const float* __restrict__ w,
                          const float* __restrict__ b, bf16* __restrict__ o){
  int r = blockIdx.x;
  int tid = threadIdx.x; /* 128 */
  const float* xr = x + (size_t)r*D_MODEL;
  float v[3];
  float s = 0.f, sq = 0.f;
  #pragma unroll
  for (int e=0;e<3;e++){ v[e]=xr[tid+128*e]; s+=v[e]; sq+=v[e]*v[e]; }
  __shared__ float reds[128], redq[128];
  reds[tid]=s; redq[tid]=sq; __syncthreads();
  for (int off=64; off>0; off>>=1){
    if (tid<off){ reds[tid]+=reds[tid+off]; redq[tid]+=redq[tid+off]; }
    __syncthreads();
  }
  float mu = reds[0]*(1.f/D_MODEL);
  float var = redq[0]*(1.f/D_MODEL) - mu*mu;
  var = var < 0.f ? 0.f : var;
  float rstd = rsqrtf(var + 1e-12f);
  bf16* orow = o + (size_t)r*D_MODEL;
  #pragma unroll
  for (int e=0;e<3;e++){
    int c=tid+128*e;
    orow[c] = __float2bfloat16((v[e]-mu)*rstd*w[c] + b[c]);
  }
}

/* ------- bf16 MFMA GEMM: MODE 0: fp32 += ; MODE 1: bf16 zxb + fp32 dtraw ------- */
template<int MODE>
__global__ __launch_bounds__(256) void mfma_gemm(
    const unsigned short* __restrict__ A,   /* M x K bf16, row-major */
    const unsigned short* __restrict__ Bt,  /* Npad x K bf16 (B transposed) */
    float* __restrict__ Cf,                 /* MODE0: M x ldc fp32 (accum) */
    unsigned short* __restrict__ Cbf,       /* MODE1: M x ZXB_LD bf16 */
    float* __restrict__ dtraw,              /* MODE1: M x 8 fp32 */
    int N, int K, int ldc){
  __shared__ __align__(16) unsigned short As[128*32];
  __shared__ __align__(16) unsigned short Bs[128*32];
  const int tid = threadIdx.x;
  const int wave = tid >> 6, lane = tid & 63;
  const int lq = lane >> 4, lm = lane & 15;
  const int m0 = blockIdx.y * 128, n0 = blockIdx.x * 128;
  const int wm = (wave >> 1) * 64, wn = (wave & 1) * 64;
  f32x4_t acc[4][4];
  #pragma unroll
  for (int i=0;i<4;i++)
    #pragma unroll
    for (int j=0;j<4;j++)
      acc[i][j] = (f32x4_t){0.f,0.f,0.f,0.f};

  for (int k0 = 0; k0 < K; k0 += 32){
    if (k0) __syncthreads();
    #pragma unroll
    for (int q=0;q<2;q++){
      int o = q*4096 + wave*1024 + lane*16;
      int m = o >> 6;
      int kb = o & 63;
      const unsigned short* ga = A  + (size_t)(m0+m)*K + k0 + (kb>>1);
      __builtin_amdgcn_global_load_lds(
          (const __attribute__((address_space(1))) void*)ga,
          (__attribute__((address_space(3))) void*)((char*)As + o), 16, 0, 0);
      const unsigned short* gb = Bt + (size_t)(n0+m)*K + k0 + (kb>>1);
      __builtin_amdgcn_global_load_lds(
          (const __attribute__((address_space(1))) void*)gb,
          (__attribute__((address_space(3))) void*)((char*)Bs + o), 16, 0, 0);
    }
    __syncthreads();
    bf16x8_t af[4], bfv[4];
    #pragma unroll
    for (int i=0;i<4;i++)
      af[i]  = *(const bf16x8_t*)(As + (wm + i*16 + lm)*32 + lq*8);
    #pragma unroll
    for (int j=0;j<4;j++)
      bfv[j] = *(const bf16x8_t*)(Bs + (wn + j*16 + lm)*32 + lq*8);
    #pragma unroll
    for (int i=0;i<4;i++)
      #pragma unroll
      for (int j=0;j<4;j++)
        acc[i][j] = __builtin_amdgcn_mfma_f32_16x16x32_bf16(af[i], bfv[j], acc[i][j], 0, 0, 0);
  }
  #pragma unroll
  for (int i=0;i<4;i++){
    int row = m0 + wm + i*16 + lq*4;
    #pragma unroll
    for (int j=0;j<4;j++){
      int col = n0 + wn + j*16 + lm;
      if (MODE == 0){
        if (col < N){
          float* cp = Cf + (size_t)row*ldc + col;
          #pragma unroll
          for (int r=0;r<4;r++)
            cp[(size_t)r*ldc] += acc[i][j][r];
        }
      } else {
        if (col < ZXB_LD){
          #pragma unroll
          for (int r=0;r<4;r++)
            Cbf[(size_t)(row+r)*ZXB_LD + col] = f_to_bits(acc[i][j][r]);
        } else if (col < N){
          int c8 = col - ZXB_LD;   /* dt columns 1664..1671 */
          #pragma unroll
          for (int r=0;r<4;r++)
            dtraw[(size_t)(row+r)*8 + c8] = acc[i][j][r];
        }
      }
    }
  }
}

/* ==== fused conv(k=4)+silu + dt/softplus + cumsum + chunked-SSD matmuls ======== */
__global__ __launch_bounds__(256) void fused_scan_kernel(
    const unsigned short* __restrict__ zxb, const float* __restrict__ dtraw,
    const float* __restrict__ cw, const float* __restrict__ cb,
    const float* __restrict__ dt_bias, const float* __restrict__ A_log,
    const float* __restrict__ D_skip,
    float* __restrict__ cumb, float* __restrict__ Dc,
    unsigned short* __restrict__ Cb, unsigned short* __restrict__ Sb,
    unsigned short* __restrict__ y){
  __shared__ __align__(16) unsigned short XshT[192*40];  /* X^T[p_local][t] */
  __shared__ __align__(16) unsigned short BshT[64*40];   /* B^T[n][t] */
  __shared__ __align__(16) unsigned short Bsh[32*72];    /* B[t][n] */
  __shared__ __align__(16) unsigned short Csh[32*72];    /* C[t][n] */
  __shared__ __align__(16) unsigned short Msh[2*32*40];  /* M~ per head */
  __shared__ float dtsh[64], Lsh[64], wsh[64];
  const int tid = threadIdx.x;
  const int bid = blockIdx.x;
  const int hp = bid & 3, c = (bid >> 2) & 31, b = bid >> 7;
  const int h_base = hp*2;
  const int t0 = c*CHUNK;

  /* ---- dt + raw log-decay for this block's 2 heads ---- */
  if (tid < 64){
    int hi = tid >> 5, t = tid & 31;
    int hg = h_base + hi;
    float raw = dtraw[(size_t)(b*SEQ + t0 + t)*8 + hg];
    float dtv_ = softplus_f(raw + dt_bias[hg]);
    dtsh[tid] = dtv_;
    Lsh[tid]  = dtv_ * (-expf(A_log[hg]));
  }

  /* ---- conv: thread-per-column, rolling 4-tap window, silu -> LDS ---- */
  #pragma unroll
  for (int it=0; it<2; it++){
    int ci = it*256 + tid;
    if (ci < 320){
      int gcol;             /* column in zxb */
      if (ci < 192) gcol = D_INNER + (h_base + ci/96)*HEADDIM + (ci%96);
      else          gcol = D_INNER + D_INNER + (ci - 192);   /* B/C: 1536.. */
      int cch = gcol - D_INNER;                              /* conv channel */
      float4 w4 = *(const float4*)(cw + cch*4);
      float bias = cb[cch];
      const unsigned short* src = zxb + (size_t)b*SEQ*ZXB_LD + gcol;
      float v0=0.f,v1=0.f,v2=0.f,v3=0.f;
      unsigned prev = 0;
      for (int t=-3; t<32; t++){
        int l = t0 + t;
        float nv = (l >= 0) ? bits_to_f(src[(size_t)l*ZXB_LD]) : 0.f;
        v0=v1; v1=v2; v2=v3; v3=nv;
        if (t < 0) continue;
        float a = silu_f(bias + w4.x*v0 + w4.y*v1 + w4.z*v2 + w4.w*v3);
        unsigned short ub = f_to_bits(a);
        if (ci < 192){
          if (t & 1) *(unsigned*)&XshT[ci*40 + (t-1)] = prev | ((unsigned)ub<<16);
          else prev = ub;
        } else if (cch < CONV_DIM - D_STATE){      /* B: cch 768..831 */
          int n = cch - D_INNER;
          Bsh[t*72 + n] = ub;
          if (t & 1) *(unsigned*)&BshT[n*40 + (t-1)] = prev | ((unsigned)ub<<16);
          else prev = ub;
        } else {                                    /* C: cch 832..895 */
          Csh[t*72 + (cch - D_INNER - D_STATE)] = ub;
        }
      }
    }
  }
  __syncthreads();

  /* ---- sequential cumsum of log-decay; chunk decay products; w-scale ---- */
  if (tid < 2){
    int hg = h_base + tid;
    float L = 0.f;
    float* cbp = cumb + ((size_t)((b*NC + c)*NHEADS) + hg)*CHUNK;
    for (int t=0;t<32;t++){
      L += Lsh[tid*32+t];
      Lsh[tid*32+t] = L;
      cbp[t] = __expf(L);
    }
    Dc[(b*NHEADS + hg)*NC + c] = __expf(L);
    for (int t=0;t<32;t++)
      wsh[tid*32+t] = __expf(L - Lsh[tid*32+t]) * dtsh[tid*32+t];
  }
  __syncthreads();

  const int wave = tid >> 6, lane = tid & 63;
  const int lq = lane >> 4, lm = lane & 15;
  const f32x4_t zero = (f32x4_t){0.f,0.f,0.f,0.f};

  /* ---- waves 0,1: G = C.B^T then M~ (D-skip on diagonal); waves 2,3: Cb out ---- */
  if (wave < 2){
    f32x4_t G[2][2];
    #pragma unroll
    for (int i=0;i<2;i++){ G[i][0]=zero; G[i][1]=zero; }
    #pragma unroll
    for (int kt=0; kt<2; kt++){
      bf16x8_t ca[2], bb[2];
      #pragma unroll
      for (int ti=0;ti<2;ti++)
        ca[ti] = *(const bf16x8_t*)&Csh[(lm+ti*16)*72 + kt*32 + lq*8];
      #pragma unroll
      for (int si=0;si<2;si++)
        bb[si] = *(const bf16x8_t*)&Bsh[(lm+si*16)*72 + kt*32 + lq*8];
      #pragma unroll
      for (int ti=0;ti<2;ti++)
        #pragma unroll
        for (int si=0;si<2;si++)
          G[ti][si] = __builtin_amdgcn_mfma_f32_16x16x32_bf16(ca[ti], bb[si], G[ti][si], 0,0,0);
    }
    int hi = wave;
    float Dk = D_skip[h_base + hi];
    float Lss[2], dts[2];
    #pragma unroll
    for (int si=0;si<2;si++){ Lss[si]=Lsh[hi*32+si*16+lm]; dts[si]=dtsh[hi*32+si*16+lm]; }
    #pragma unroll
    for (int ti=0;ti<2;ti++){
      #pragma unroll
      for (int r=0;r<4;r++){
        int t = ti*16 + lq*4 + r;
        float Lt = Lsh[hi*32 + t];
        #pragma unroll
        for (int si=0;si<2;si++){
          int s = si*16 + lm;
          float m = 0.f;
          if (s <= t){
            m = G[ti][si][r]*__expf(Lt - Lss[si])*dts[si];
            if (s == t) m += Dk;
          }
          Msh[hi*1280 + t*40 + s] = f_to_bits(m);
        }
      }
    }
  } else if (hp == 0){
    int lt = tid - 128;
    for (int i = lt; i < 512; i += 128){
      int t = i >> 4, q = i & 15;
      *(ushort4*)(Cb + ((size_t)(b*SEQ) + t0 + t)*D_STATE + q*4) =
          *(const ushort4*)&Csh[t*72 + q*4];
    }
  }
  __syncthreads();

  /* ---- compute: wave -> (head hi = wave&1, pt-half = wave>>1) ---- */
  {
    int hi = wave & 1, hg = h_base + hi;
    int ptb = (wave >> 1)*3;
    bf16x8_t mf[2];
    #pragma unroll
    for (int tt=0;tt<2;tt++)
      mf[tt] = *(const bf16x8_t*)&Msh[hi*1280 + (lm+tt*16)*40 + lq*8];
    float wv[8];
    #pragma unroll
    for (int j=0;j<8;j++) wv[j] = wsh[hi*32 + lq*8 + j];
    bf16x8_t bw[4];
    #pragma unroll
    for (int nt=0;nt<4;nt++){
      bf16x8_t raw = *(const bf16x8_t*)&BshT[(lm+nt*16)*40 + lq*8];
      #pragma unroll
      for (int j=0;j<8;j++)
        bw[nt][j] = (short)f_to_bits(bits_to_f((unsigned short)raw[j]) * wv[j]);
    }
    const size_t sbase = ((size_t)((b*NC + c)*NHEADS) + hg)*HEADDIM*D_STATE;
    #pragma unroll
    for (int pp=0; pp<3; pp++){
      int pt = ptb + pp;
      bf16x8_t xf = *(const bf16x8_t*)&XshT[(hi*96 + pt*16 + lm)*40 + lq*8];
      /* Y1 (+ D*x via diagonal) */
      #pragma unroll
      for (int tt=0;tt<2;tt++){
        f32x4_t a = __builtin_amdgcn_mfma_f32_16x16x32_bf16(mf[tt], xf, zero, 0,0,0);
        #pragma unroll
        for (int r=0;r<4;r++){
          int t = tt*16 + lq*4 + r;
          y[((size_t)(b*SEQ) + t0 + t)*D_INNER + hg*HEADDIM + pt*16 + lm] = f_to_bits(a[r]);
        }
      }
      /* S = X^T @ (w.B) */
      #pragma unroll
      for (int nt=0;nt<4;nt++){
        f32x4_t s = __builtin_amdgcn_mfma_f32_16x16x32_bf16(xf, bw[nt], zero, 0,0,0);
        #pragma unroll
        for (int r=0;r<4;r++){
          int p = pt*16 + lq*4 + r;
          Sb[sbase + (size_t)p*D_STATE + nt*16 + lm] = f_to_bits(s[r]);
        }
      }
    }
  }
}

/* ---- sequential chunk combine on bf16 S (in-place -> Hin) --------------------- */
__global__ __launch_bounds__(256) void combine_kernel(
    unsigned short* __restrict__ S, const float* __restrict__ Dc){
  int g = blockIdx.x*256 + threadIdx.x;     /* (b,h,p,nq): 8*8*96*16 = 98304 */
  int nq = g & 15;
  int p  = (g >> 4) % 96;
  int h  = (g / (16*96)) & 7;
  int b  = g / (16*96*8);
  const float* Dp = Dc + (size_t)(b*NHEADS + h)*NC;
  float H0=0.f,H1=0.f,H2=0.f,H3=0.f;
  for (int c=0;c<NC;c++){
    size_t base = ((((size_t)(b*NC + c)*NHEADS + h)*HEADDIM + p)*D_STATE + nq*4);
    ushort4 s = *(ushort4*)(S + base);
    float s0=bits_to_f(s.x), s1=bits_to_f(s.y), s2=bits_to_f(s.z), s3=bits_to_f(s.w);
    *(ushort4*)(S + base) = make_ushort4(f_to_bits(H0),f_to_bits(H1),f_to_bits(H2),f_to_bits(H3));
    float D = Dp[c];
    H0 = fmaf(D,H0,s0); H1 = fmaf(D,H1,s1); H2 = fmaf(D,H2,s2); H3 = fmaf(D,H3,s3);
  }
}

/* ==== fused: y_final = y + cum*(C@Hin^T); gate with silu(z); RMSNorm -> ygb ==== */
__global__ __launch_bounds__(256) void hinfuse_kernel(
    const unsigned short* __restrict__ Cb, const unsigned short* __restrict__ Hinb,
    const float* __restrict__ cumb, const unsigned short* __restrict__ zxb,
    const float* __restrict__ nw, const unsigned short* __restrict__ ybuf,
    unsigned short* __restrict__ ygb){
  __shared__ __align__(16) unsigned short Vsh[32*VP];
  __shared__ float cumsh[256];
  __shared__ float rowsq[32];
  const int tid = threadIdx.x;
  const int c = blockIdx.x & 31, b = blockIdx.x >> 5;
  const int t0 = c*CHUNK;
  cumsh[tid] = cumb[(size_t)((b*NC + c)*NHEADS)*CHUNK + tid];   /* h=tid>>5,t=tid&31 */
  if (tid < 32) rowsq[tid] = 0.f;
  __syncthreads();
  const int wave = tid >> 6, lane = tid & 63;
  const int lq = lane >> 4, lm = lane & 15;
  const f32x4_t zero = (f32x4_t){0.f,0.f,0.f,0.f};
  float sql[2][4] = {};
  for (int hh=0; hh<2; hh++){
    int h = wave*2 + hh;
    const unsigned short* Hb = Hinb + ((size_t)((b*NC + c)*NHEADS) + h)*HEADDIM*D_STATE;
    bf16x8_t ca[2][2];
    #pragma unroll
    for (int tt=0;tt<2;tt++)
      #pragma unroll
      for (int kt=0;kt<2;kt++)
        ca[tt][kt] = *(const bf16x8_t*)(Cb +
            ((size_t)(b*SEQ) + t0 + tt*16 + lm)*D_STATE + kt*32 + lq*8);
    #pragma unroll
    for (int pt=0; pt<6; pt++){
      bf16x8_t hf0 = *(const bf16x8_t*)&Hb[(size_t)(lm+pt*16)*D_STATE + lq*8];
      bf16x8_t hf1 = *(const bf16x8_t*)&Hb[(size_t)(lm+pt*16)*D_STATE + 32 + lq*8];
      f32x4_t acc[2];
      #pragma unroll
      for (int tt=0;tt<2;tt++){
        acc[tt] = __builtin_amdgcn_mfma_f32_16x16x32_bf16(ca[tt][0], hf0, zero, 0,0,0);
        acc[tt] = __builtin_amdgcn_mfma_f32_16x16x32_bf16(ca[tt][1], hf1, acc[tt], 0,0,0);
      }
      int pcol = h*HEADDIM + pt*16 + lm;
      #pragma unroll
      for (int tt=0;tt<2;tt++){
        #pragma unroll
        for (int r=0;r<4;r++){
          int t = tt*16 + lq*4 + r;
          size_t row = (size_t)(b*SEQ) + t0 + t;
          float yv = bits_to_f(ybuf[row*D_INNER + pcol]) + cumsh[h*32+t]*acc[tt][r];
          float z  = bits_to_f(zxb[row*ZXB_LD + pcol]);
          float v  = yv * silu_f(z);
          Vsh[t*VP + pcol] = f_to_bits(v);
          sql[tt][r] += v*v;
        }
      }
    }
  }
  /* reduce v^2 over the 16 lm lanes, then one LDS atomic per (t) per wave */
  #pragma unroll
  for (int tt=0;tt<2;tt++)
    #pragma unroll
    for (int r=0;r<4;r++){
      float v = sql[tt][r];
      v += __shfl_xor(v,1); v += __shfl_xor(v,2);
      v += __shfl_xor(v,4); v += __shfl_xor(v,8);
      if (lm == 0) atomicAdd(&rowsq[tt*16 + lq*4 + r], v);
    }
  __syncthreads();
  if (tid < 32) rowsq[tid] = rsqrtf(rowsq[tid]*(1.f/D_INNER) + 1e-5f);
  __syncthreads();
  for (int i=tid; i<32*192; i+=256){
    int t = i/192, q = i%192;
    ushort4 pv = *(const ushort4*)&Vsh[t*VP + q*4];
    float rms = rowsq[t];
    float4 w4 = *(const float4*)(nw + q*4);
    ushort4 o;
    o.x = f_to_bits(bits_to_f(pv.x)*rms*w4.x);
    o.y = f_to_bits(bits_to_f(pv.y)*rms*w4.y);
    o.z = f_to_bits(bits_to_f(pv.z)*rms*w4.z);
    o.w = f_to_bits(bits_to_f(pv.w)*rms*w4.w);
    *(ushort4*)(ygb + ((size_t)(b*SEQ) + t0 + t)*D_INNER + q*4) = o;
  }
}

extern "C" void kernel_launch(void* const* d_in, const int* in_sizes, int n_in,
                              void* d_out, int out_size, void* d_ws, size_t ws_size,
                              hipStream_t stream){
  const float* x0      = (const float*)d_in[0];
  const float* ln_w    = (const float*)d_in[1];
  const float* ln_b    = (const float*)d_in[2];
  const float* W_in    = (const float*)d_in[3];
  const float* conv_w  = (const float*)d_in[4];
  const float* conv_b  = (const float*)d_in[5];
  const float* dt_bias = (const float*)d_in[6];
  const float* A_log   = (const float*)d_in[7];
  const float* D_skip  = (const float*)d_in[8];
  const float* norm_w  = (const float*)d_in[9];
  const float* W_out   = (const float*)d_in[10];
  float* out = (float*)d_out;

  /* workspace (float units), ~91 MB */
  float* p    = (float*)d_ws;
  unsigned short* zxb = (unsigned short*)p;   p += (size_t)ROWS*ZXB_LD/2;
  float* dtraw = p;  p += (size_t)ROWS*8;
  float* cumb  = p;  p += (size_t)BATCH*NHEADS*SEQ;
  float* Dc    = p;  p += (size_t)BATCH*NHEADS*NC;
  unsigned short* ybuf = (unsigned short*)p;  p += (size_t)ROWS*D_INNER/2;
  unsigned short* ygb  = (unsigned short*)p;  p += (size_t)ROWS*D_INNER/2;
  unsigned short* Sb   = (unsigned short*)p;  p += (size_t)BATCH*NC*NHEADS*HEADDIM*D_STATE/2;
  unsigned short* Cb   = (unsigned short*)p;  p += (size_t)ROWS*D_STATE/2;
  bf16* Wt  = (bf16*)p; p += (size_t)NUM_LAYERS*NPAD_IN*D_MODEL/2;
  bf16* Wot = (bf16*)p;
  bf16* hnb = (bf16*)Sb;   /* alias: live ln -> gemm_in, dead before fused_scan */

  hipMemcpyAsync(out, x0, (size_t)ROWS*D_MODEL*sizeof(float),
                 hipMemcpyDeviceToDevice, stream);

  wconv_kernel<<<dim3(NPAD_IN/32, D_MODEL/32, NUM_LAYERS), dim3(32,8), 0, stream>>>(
      W_in, Wt, D_MODEL, D_IN_PROJ, NPAD_IN);
  wconv_kernel<<<dim3(NPAD_OUT/32, D_INNER/32, NUM_LAYERS), dim3(32,8), 0, stream>>>(
      W_out, Wot, D_INNER, D_MODEL, NPAD_OUT);

  for (int i=0;i<NUM_LAYERS;i++){
    ln_kernel<<<ROWS,128,0,stream>>>(out, ln_w+(size_t)i*D_MODEL, ln_b+(size_t)i*D_MODEL, hnb);
    mfma_gemm<1><<<dim3(NPAD_IN/128, ROWS/128), 256, 0, stream>>>(
        (const unsigned short*)hnb, (const unsigned short*)(Wt + (size_t)i*NPAD_IN*D_MODEL),
        nullptr, zxb, dtraw, D_IN_PROJ, D_MODEL, 0);
    fused_scan_kernel<<<BATCH*NC*4, 256, 0, stream>>>(
        zxb, dtraw, conv_w + (size_t)i*CONV_DIM*4, conv_b + (size_t)i*CONV_DIM,
        dt_bias+(size_t)i*NHEADS, A_log+(size_t)i*NHEADS, D_skip+(size_t)i*NHEADS,
        cumb, Dc, Cb, Sb, ybuf);
    combine_kernel<<<(BATCH*NHEADS*HEADDIM*16)/256, 256, 0, stream>>>(Sb, Dc);
    hinfuse_kernel<<<BATCH*NC, 256, 0, stream>>>(
        Cb, Sb, cumb, zxb, norm_w+(size_t)i*D_INNER, ybuf, ygb);
    mfma_gemm<0><<<dim3(NPAD_OUT/128, ROWS/128), 256, 0, stream>>>(
        (const unsigned short*)ygb, (const unsigned short*)(Wot + (size_t)i*NPAD_OUT*D_INNER),
        out, nullptr, nullptr, D_MODEL, D_INNER, D_MODEL);
  }
}

// Round 7
// 828.981 us; speedup vs baseline: 14.2102x; 1.0244x over previous
//
#include <hip/hip_runtime.h>
#include <hip/hip_bf16.h>
#include <math.h>

#define D_MODEL 384
#define D_STATE 64
#define D_INNER 768
#define HEADDIM 96
#define NHEADS 8
#define CONV_DIM 896
#define D_IN_PROJ 1672
#define ZXB_LD 1664        /* bf16 zx row stride (z,X,B,C); dt split to fp32 */
#define BATCH 8
#define SEQ 1024
#define ROWS (BATCH*SEQ)   /* 8192 */
#define NUM_LAYERS 6
#define NC 32              /* chunks */
#define CHUNK 32           /* timesteps per chunk */
#define NPAD_IN 1792       /* 14 * 128 */
#define NPAD_OUT 384       /* 3 * 128  */
#define VP 776             /* padded Vsh row (shorts) */

typedef __hip_bfloat16 bf16;
using bf16x8_t = __attribute__((ext_vector_type(8))) short;
using f32x4_t  = __attribute__((ext_vector_type(4))) float;

__device__ __forceinline__ float softplus_f(float v){
  return v > 20.f ? v : log1pf(expf(v));
}
__device__ __forceinline__ float silu_f(float v){
  return v / (1.f + expf(-v));
}
__device__ __forceinline__ float bits_to_f(unsigned short u){
  union{unsigned u32; float f;} cv; cv.u32 = ((unsigned)u)<<16; return cv.f;
}
__device__ __forceinline__ unsigned short f_to_bits(float f){
  union{bf16 b; unsigned short u;} cv; cv.b = __float2bfloat16(f); return cv.u;
}

/* ------- weight transpose + fp32->bf16, all layers batched via grid.z ---------- */
__global__ void wconv_kernel(const float* __restrict__ W, bf16* __restrict__ Wt,
                             int K, int N, int Npad){
  __shared__ float tile[32][33];
  W  += (size_t)blockIdx.z*K*N;
  Wt += (size_t)blockIdx.z*Npad*K;
  int kb = blockIdx.y*32, nb = blockIdx.x*32;
  int tx = threadIdx.x, ty = threadIdx.y;   /* 32 x 8 */
  #pragma unroll
  for (int r=0;r<32;r+=8){
    int k = kb+ty+r, n = nb+tx;
    tile[ty+r][tx] = (k<K && n<N) ? W[(size_t)k*N+n] : 0.f;
  }
  __syncthreads();
  #pragma unroll
  for (int r=0;r<32;r+=8){
    int n = nb+ty+r, k = kb+tx;
    if (n<Npad && k<K) Wt[(size_t)n*K+k] = __float2bfloat16(tile[tx][ty+r]);
  }
}

/* ---------------- LayerNorm: one block (128 thr) per row of 384 -> bf16 -------- */
__global__ void ln_kernel(const float* __restrict__ x, const float* __restrict__ w,
                          const float* __restrict__ b, bf16* __restrict__ o){
  int r = blockIdx.x;
  int tid = threadIdx.x; /* 128 */
  const float* xr = x + (size_t)r*D_MODEL;
  float v[3];
  float s = 0.f, sq = 0.f;
  #pragma unroll
  for (int e=0;e<3;e++){ v[e]=xr[tid+128*e]; s+=v[e]; sq+=v[e]*v[e]; }
  __shared__ float reds[128], redq[128];
  reds[tid]=s; redq[tid]=sq; __syncthreads();
  for (int off=64; off>0; off>>=1){
    if (tid<off){ reds[tid]+=reds[tid+off]; redq[tid]+=redq[tid+off]; }
    __syncthreads();
  }
  float mu = reds[0]*(1.f/D_MODEL);
  float var = redq[0]*(1.f/D_MODEL) - mu*mu;
  var = var < 0.f ? 0.f : var;
  float rstd = rsqrtf(var + 1e-12f);
  bf16* orow = o + (size_t)r*D_MODEL;
  #pragma unroll
  for (int e=0;e<3;e++){
    int c=tid+128*e;
    orow[c] = __float2bfloat16((v[e]-mu)*rstd*w[c] + b[c]);
  }
}

/* ------- bf16 MFMA GEMM: MODE 0: fp32 += ; MODE 1: bf16 zxb + fp32 dtraw -------
   Epilogues vectorized via LDS bounce (smem reused after K-loop).              */
template<int MODE>
__global__ __launch_bounds__(256) void mfma_gemm(
    const unsigned short* __restrict__ A,   /* M x K bf16, row-major */
    const unsigned short* __restrict__ Bt,  /* Npad x K bf16 (B transposed) */
    float* __restrict__ Cf,                 /* MODE0: M x ldc fp32 (accum) */
    unsigned short* __restrict__ Cbf,       /* MODE1: M x ZXB_LD bf16 */
    float* __restrict__ dtraw,              /* MODE1: M x 8 fp32 */
    int N, int K, int ldc){
  __shared__ __align__(16) unsigned short smem[128*136];  /* 34 KB */
  unsigned short* As = smem;          /* 128*32 */
  unsigned short* Bs = smem + 4096;   /* 128*32 */
  const int tid = threadIdx.x;
  const int wave = tid >> 6, lane = tid & 63;
  const int lq = lane >> 4, lm = lane & 15;
  const int m0 = blockIdx.y * 128, n0 = blockIdx.x * 128;
  const int wm = (wave >> 1) * 64, wn = (wave & 1) * 64;
  f32x4_t acc[4][4];
  #pragma unroll
  for (int i=0;i<4;i++)
    #pragma unroll
    for (int j=0;j<4;j++)
      acc[i][j] = (f32x4_t){0.f,0.f,0.f,0.f};

  for (int k0 = 0; k0 < K; k0 += 32){
    if (k0) __syncthreads();
    #pragma unroll
    for (int q=0;q<2;q++){
      int o = q*4096 + wave*1024 + lane*16;
      int m = o >> 6;
      int kb = o & 63;
      const unsigned short* ga = A  + (size_t)(m0+m)*K + k0 + (kb>>1);
      __builtin_amdgcn_global_load_lds(
          (const __attribute__((address_space(1))) void*)ga,
          (__attribute__((address_space(3))) void*)((char*)As + o), 16, 0, 0);
      const unsigned short* gb = Bt + (size_t)(n0+m)*K + k0 + (kb>>1);
      __builtin_amdgcn_global_load_lds(
          (const __attribute__((address_space(1))) void*)gb,
          (__attribute__((address_space(3))) void*)((char*)Bs + o), 16, 0, 0);
    }
    __syncthreads();
    bf16x8_t af[4], bfv[4];
    #pragma unroll
    for (int i=0;i<4;i++)
      af[i]  = *(const bf16x8_t*)(As + (wm + i*16 + lm)*32 + lq*8);
    #pragma unroll
    for (int j=0;j<4;j++)
      bfv[j] = *(const bf16x8_t*)(Bs + (wn + j*16 + lm)*32 + lq*8);
    #pragma unroll
    for (int i=0;i<4;i++)
      #pragma unroll
      for (int j=0;j<4;j++)
        acc[i][j] = __builtin_amdgcn_mfma_f32_16x16x32_bf16(af[i], bfv[j], acc[i][j], 0, 0, 0);
  }

  if (MODE == 1){
    if (n0 == ZXB_LD){
      /* dt block: local cols 0..7 are dt (fp32 direct); rest is padding */
      if ((wave & 1) == 0 && lm < 8){
        #pragma unroll
        for (int i=0;i<4;i++){
          int row = m0 + wm + i*16 + lq*4;
          #pragma unroll
          for (int r=0;r<4;r++)
            dtraw[(size_t)(row+r)*8 + lm] = acc[i][0][r];
        }
      }
      return;
    }
    __syncthreads();   /* done reading As/Bs: reuse smem as C-stage */
    #pragma unroll
    for (int i=0;i<4;i++){
      int rl = wm + i*16 + lq*4;
      #pragma unroll
      for (int j=0;j<4;j++){
        int cl = wn + j*16 + lm;
        #pragma unroll
        for (int r=0;r<4;r++)
          smem[(rl+r)*136 + cl] = f_to_bits(acc[i][j][r]);
      }
    }
    __syncthreads();
    /* 2 threads/row, 8x 16B stores each */
    {
      int row = tid >> 1;
      int cbase = (tid & 1) * 64;
      size_t gb = (size_t)(m0 + row) * ZXB_LD + n0 + cbase;
      #pragma unroll
      for (int k=0;k<8;k++)
        *(bf16x8_t*)(Cbf + gb + k*8) = *(const bf16x8_t*)&smem[row*136 + cbase + k*8];
    }
  } else {
    /* MODE 0: accumulate into fp32 out; two 64-row halves through LDS */
    float* smf = (float*)smem;   /* 64 x 132 fp32 = 33792 B */
    #pragma unroll
    for (int h=0;h<2;h++){
      __syncthreads();
      if ((wave >> 1) == h){
        #pragma unroll
        for (int i=0;i<4;i++){
          int rl = i*16 + lq*4;            /* wm-relative */
          #pragma unroll
          for (int j=0;j<4;j++){
            int cl = wn + j*16 + lm;
            #pragma unroll
            for (int r=0;r<4;r++)
              smf[(rl+r)*132 + cl] = acc[i][j][r];
          }
        }
      }
      __syncthreads();
      int row = tid >> 2;
      int cbase = (tid & 3) * 32;
      float* gp = Cf + (size_t)(m0 + h*64 + row)*ldc + n0 + cbase;
      #pragma unroll
      for (int k=0;k<8;k++){
        float4 v = *(float4*)(gp + k*4);
        float4 a = *(const float4*)&smf[row*132 + cbase + k*4];
        v.x+=a.x; v.y+=a.y; v.z+=a.z; v.w+=a.w;
        *(float4*)(gp + k*4) = v;
      }
    }
  }
}

/* ==== fused conv(k=4)+silu + dt/softplus + cumsum + chunked-SSD matmuls ======== */
__global__ __launch_bounds__(256) void fused_scan_kernel(
    const unsigned short* __restrict__ zxb, const float* __restrict__ dtraw,
    const float* __restrict__ cw, const float* __restrict__ cb,
    const float* __restrict__ dt_bias, const float* __restrict__ A_log,
    const float* __restrict__ D_skip,
    float* __restrict__ cumb, float* __restrict__ Dc,
    unsigned short* __restrict__ Cb, unsigned short* __restrict__ Sb,
    unsigned short* __restrict__ y){
  __shared__ __align__(16) unsigned short XshT[192*40];  /* X^T[p_local][t] */
  __shared__ __align__(16) unsigned short BshT[64*40];   /* B^T[n][t] */
  __shared__ __align__(16) unsigned short Bsh[32*72];    /* B[t][n] */
  __shared__ __align__(16) unsigned short Csh[32*72];    /* C[t][n] */
  __shared__ __align__(16) unsigned short Msh[2*32*40];  /* M~ per head */
  __shared__ float dtsh[64], Lsh[64], wsh[64];
  const int tid = threadIdx.x;
  const int bid = blockIdx.x;
  const int hp = bid & 3, c = (bid >> 2) & 31, b = bid >> 7;
  const int h_base = hp*2;
  const int t0 = c*CHUNK;

  /* ---- dt + raw log-decay for this block's 2 heads ---- */
  if (tid < 64){
    int hi = tid >> 5, t = tid & 31;
    int hg = h_base + hi;
    float raw = dtraw[(size_t)(b*SEQ + t0 + t)*8 + hg];
    float dtv_ = softplus_f(raw + dt_bias[hg]);
    dtsh[tid] = dtv_;
    Lsh[tid]  = dtv_ * (-expf(A_log[hg]));
  }

  /* ---- conv: thread-per-column, rolling 4-tap window, silu -> LDS ---- */
  #pragma unroll
  for (int it=0; it<2; it++){
    int ci = it*256 + tid;
    if (ci < 320){
      int gcol;             /* column in zxb */
      if (ci < 192) gcol = D_INNER + (h_base + ci/96)*HEADDIM + (ci%96);
      else          gcol = D_INNER + D_INNER + (ci - 192);   /* B/C: 1536.. */
      int cch = gcol - D_INNER;                              /* conv channel */
      float4 w4 = *(const float4*)(cw + cch*4);
      float bias = cb[cch];
      const unsigned short* src = zxb + (size_t)b*SEQ*ZXB_LD + gcol;
      float v0=0.f,v1=0.f,v2=0.f,v3=0.f;
      unsigned prev = 0;
      for (int t=-3; t<32; t++){
        int l = t0 + t;
        float nv = (l >= 0) ? bits_to_f(src[(size_t)l*ZXB_LD]) : 0.f;
        v0=v1; v1=v2; v2=v3; v3=nv;
        if (t < 0) continue;
        float a = silu_f(bias + w4.x*v0 + w4.y*v1 + w4.z*v2 + w4.w*v3);
        unsigned short ub = f_to_bits(a);
        if (ci < 192){
          if (t & 1) *(unsigned*)&XshT[ci*40 + (t-1)] = prev | ((unsigned)ub<<16);
          else prev = ub;
        } else if (cch < CONV_DIM - D_STATE){      /* B: cch 768..831 */
          int n = cch - D_INNER;
          Bsh[t*72 + n] = ub;
          if (t & 1) *(unsigned*)&BshT[n*40 + (t-1)] = prev | ((unsigned)ub<<16);
          else prev = ub;
        } else {                                    /* C: cch 832..895 */
          Csh[t*72 + (cch - D_INNER - D_STATE)] = ub;
        }
      }
    }
  }
  __syncthreads();

  /* ---- sequential cumsum of log-decay; chunk decay products; w-scale ---- */
  if (tid < 2){
    int hg = h_base + tid;
    float L = 0.f;
    float* cbp = cumb + ((size_t)((b*NC + c)*NHEADS) + hg)*CHUNK;
    for (int t=0;t<32;t++){
      L += Lsh[tid*32+t];
      Lsh[tid*32+t] = L;
      cbp[t] = __expf(L);
    }
    Dc[(b*NHEADS + hg)*NC + c] = __expf(L);
    for (int t=0;t<32;t++)
      wsh[tid*32+t] = __expf(L - Lsh[tid*32+t]) * dtsh[tid*32+t];
  }
  __syncthreads();

  const int wave = tid >> 6, lane = tid & 63;
  const int lq = lane >> 4, lm = lane & 15;
  const f32x4_t zero = (f32x4_t){0.f,0.f,0.f,0.f};

  /* ---- waves 0,1: G = C.B^T then M~ (D-skip on diagonal); waves 2,3: Cb out ---- */
  if (wave < 2){
    f32x4_t G[2][2];
    #pragma unroll
    for (int i=0;i<2;i++){ G[i][0]=zero; G[i][1]=zero; }
    #pragma unroll
    for (int kt=0; kt<2; kt++){
      bf16x8_t ca[2], bb[2];
      #pragma unroll
      for (int ti=0;ti<2;ti++)
        ca[ti] = *(const bf16x8_t*)&Csh[(lm+ti*16)*72 + kt*32 + lq*8];
      #pragma unroll
      for (int si=0;si<2;si++)
        bb[si] = *(const bf16x8_t*)&Bsh[(lm+si*16)*72 + kt*32 + lq*8];
      #pragma unroll
      for (int ti=0;ti<2;ti++)
        #pragma unroll
        for (int si=0;si<2;si++)
          G[ti][si] = __builtin_amdgcn_mfma_f32_16x16x32_bf16(ca[ti], bb[si], G[ti][si], 0,0,0);
    }
    int hi = wave;
    float Dk = D_skip[h_base + hi];
    float Lss[2], dts[2];
    #pragma unroll
    for (int si=0;si<2;si++){ Lss[si]=Lsh[hi*32+si*16+lm]; dts[si]=dtsh[hi*32+si*16+lm]; }
    #pragma unroll
    for (int ti=0;ti<2;ti++){
      #pragma unroll
      for (int r=0;r<4;r++){
        int t = ti*16 + lq*4 + r;
        float Lt = Lsh[hi*32 + t];
        #pragma unroll
        for (int si=0;si<2;si++){
          int s = si*16 + lm;
          float m = 0.f;
          if (s <= t){
            m = G[ti][si][r]*__expf(Lt - Lss[si])*dts[si];
            if (s == t) m += Dk;
          }
          Msh[hi*1280 + t*40 + s] = f_to_bits(m);
        }
      }
    }
  } else if (hp == 0){
    int lt = tid - 128;
    for (int i = lt; i < 512; i += 128){
      int t = i >> 4, q = i & 15;
      *(ushort4*)(Cb + ((size_t)(b*SEQ) + t0 + t)*D_STATE + q*4) =
          *(const ushort4*)&Csh[t*72 + q*4];
    }
  }
  __syncthreads();

  /* ---- compute: wave -> (head hi = wave&1, pt-half = wave>>1) ---- */
  {
    int hi = wave & 1, hg = h_base + hi;
    int ptb = (wave >> 1)*3;
    bf16x8_t mf[2];
    #pragma unroll
    for (int tt=0;tt<2;tt++)
      mf[tt] = *(const bf16x8_t*)&Msh[hi*1280 + (lm+tt*16)*40 + lq*8];
    float wv[8];
    #pragma unroll
    for (int j=0;j<8;j++) wv[j] = wsh[hi*32 + lq*8 + j];
    bf16x8_t bw[4];
    #pragma unroll
    for (int nt=0;nt<4;nt++){
      bf16x8_t raw = *(const bf16x8_t*)&BshT[(lm+nt*16)*40 + lq*8];
      #pragma unroll
      for (int j=0;j<8;j++)
        bw[nt][j] = (short)f_to_bits(bits_to_f((unsigned short)raw[j]) * wv[j]);
    }
    const size_t sbase = ((size_t)((b*NC + c)*NHEADS) + hg)*HEADDIM*D_STATE;
    #pragma unroll
    for (int pp=0; pp<3; pp++){
      int pt = ptb + pp;
      bf16x8_t xf = *(const bf16x8_t*)&XshT[(hi*96 + pt*16 + lm)*40 + lq*8];
      /* Y1 (+ D*x via diagonal) */
      #pragma unroll
      for (int tt=0;tt<2;tt++){
        f32x4_t a = __builtin_amdgcn_mfma_f32_16x16x32_bf16(mf[tt], xf, zero, 0,0,0);
        #pragma unroll
        for (int r=0;r<4;r++){
          int t = tt*16 + lq*4 + r;
          y[((size_t)(b*SEQ) + t0 + t)*D_INNER + hg*HEADDIM + pt*16 + lm] = f_to_bits(a[r]);
        }
      }
      /* S = X^T @ (w.B) */
      #pragma unroll
      for (int nt=0;nt<4;nt++){
        f32x4_t s = __builtin_amdgcn_mfma_f32_16x16x32_bf16(xf, bw[nt], zero, 0,0,0);
        #pragma unroll
        for (int r=0;r<4;r++){
          int p = pt*16 + lq*4 + r;
          Sb[sbase + (size_t)p*D_STATE + nt*16 + lm] = f_to_bits(s[r]);
        }
      }
    }
  }
}

/* ---- sequential chunk combine on bf16 S (in-place -> Hin) --------------------- */
__global__ __launch_bounds__(256) void combine_kernel(
    unsigned short* __restrict__ S, const float* __restrict__ Dc){
  int g = blockIdx.x*256 + threadIdx.x;     /* (b,h,p,nq): 8*8*96*16 = 98304 */
  int nq = g & 15;
  int p  = (g >> 4) % 96;
  int h  = (g / (16*96)) & 7;
  int b  = g / (16*96*8);
  const float* Dp = Dc + (size_t)(b*NHEADS + h)*NC;
  float H0=0.f,H1=0.f,H2=0.f,H3=0.f;
  for (int c=0;c<NC;c++){
    size_t base = ((((size_t)(b*NC + c)*NHEADS + h)*HEADDIM + p)*D_STATE + nq*4);
    ushort4 s = *(ushort4*)(S + base);
    float s0=bits_to_f(s.x), s1=bits_to_f(s.y), s2=bits_to_f(s.z), s3=bits_to_f(s.w);
    *(ushort4*)(S + base) = make_ushort4(f_to_bits(H0),f_to_bits(H1),f_to_bits(H2),f_to_bits(H3));
    float D = Dp[c];
    H0 = fmaf(D,H0,s0); H1 = fmaf(D,H1,s1); H2 = fmaf(D,H2,s2); H3 = fmaf(D,H3,s3);
  }
}

/* ==== fused: y_final = y + cum*(C@Hin^T); gate with silu(z); RMSNorm -> ygb ==== */
__global__ __launch_bounds__(256) void hinfuse_kernel(
    const unsigned short* __restrict__ Cb, const unsigned short* __restrict__ Hinb,
    const float* __restrict__ cumb, const unsigned short* __restrict__ zxb,
    const float* __restrict__ nw, const unsigned short* __restrict__ ybuf,
    unsigned short* __restrict__ ygb){
  __shared__ __align__(16) unsigned short Vsh[32*VP];
  __shared__ float cumsh[256];
  __shared__ float rowsq[32];
  const int tid = threadIdx.x;
  const int c = blockIdx.x & 31, b = blockIdx.x >> 5;
  const int t0 = c*CHUNK;
  cumsh[tid] = cumb[(size_t)((b*NC + c)*NHEADS)*CHUNK + tid];   /* h=tid>>5,t=tid&31 */
  if (tid < 32) rowsq[tid] = 0.f;
  __syncthreads();
  const int wave = tid >> 6, lane = tid & 63;
  const int lq = lane >> 4, lm = lane & 15;
  const f32x4_t zero = (f32x4_t){0.f,0.f,0.f,0.f};
  float sql[2][4] = {};
  for (int hh=0; hh<2; hh++){
    int h = wave*2 + hh;
    const unsigned short* Hb = Hinb + ((size_t)((b*NC + c)*NHEADS) + h)*HEADDIM*D_STATE;
    bf16x8_t ca[2][2];
    #pragma unroll
    for (int tt=0;tt<2;tt++)
      #pragma unroll
      for (int kt=0;kt<2;kt++)
        ca[tt][kt] = *(const bf16x8_t*)(Cb +
            ((size_t)(b*SEQ) + t0 + tt*16 + lm)*D_STATE + kt*32 + lq*8);
    #pragma unroll
    for (int pt=0; pt<6; pt++){
      bf16x8_t hf0 = *(const bf16x8_t*)&Hb[(size_t)(lm+pt*16)*D_STATE + lq*8];
      bf16x8_t hf1 = *(const bf16x8_t*)&Hb[(size_t)(lm+pt*16)*D_STATE + 32 + lq*8];
      f32x4_t acc[2];
      #pragma unroll
      for (int tt=0;tt<2;tt++){
        acc[tt] = __builtin_amdgcn_mfma_f32_16x16x32_bf16(ca[tt][0], hf0, zero, 0,0,0);
        acc[tt] = __builtin_amdgcn_mfma_f32_16x16x32_bf16(ca[tt][1], hf1, acc[tt], 0,0,0);
      }
      int pcol = h*HEADDIM + pt*16 + lm;
      #pragma unroll
      for (int tt=0;tt<2;tt++){
        #pragma unroll
        for (int r=0;r<4;r++){
          int t = tt*16 + lq*4 + r;
          size_t row = (size_t)(b*SEQ) + t0 + t;
          float yv = bits_to_f(ybuf[row*D_INNER + pcol]) + cumsh[h*32+t]*acc[tt][r];
          float z  = bits_to_f(zxb[row*ZXB_LD + pcol]);
          float v  = yv * silu_f(z);
          Vsh[t*VP + pcol] = f_to_bits(v);
          sql[tt][r] += v*v;
        }
      }
    }
  }
  /* reduce v^2 over the 16 lm lanes, then one LDS atomic per (t) per wave */
  #pragma unroll
  for (int tt=0;tt<2;tt++)
    #pragma unroll
    for (int r=0;r<4;r++){
      float v = sql[tt][r];
      v += __shfl_xor(v,1); v += __shfl_xor(v,2);
      v += __shfl_xor(v,4); v += __shfl_xor(v,8);
      if (lm == 0) atomicAdd(&rowsq[tt*16 + lq*4 + r], v);
    }
  __syncthreads();
  if (tid < 32) rowsq[tid] = rsqrtf(rowsq[tid]*(1.f/D_INNER) + 1e-5f);
  __syncthreads();
  for (int i=tid; i<32*192; i+=256){
    int t = i/192, q = i%192;
    ushort4 pv = *(const ushort4*)&Vsh[t*VP + q*4];
    float rms = rowsq[t];
    float4 w4 = *(const float4*)(nw + q*4);
    ushort4 o;
    o.x = f_to_bits(bits_to_f(pv.x)*rms*w4.x);
    o.y = f_to_bits(bits_to_f(pv.y)*rms*w4.y);
    o.z = f_to_bits(bits_to_f(pv.z)*rms*w4.z);
    o.w = f_to_bits(bits_to_f(pv.w)*rms*w4.w);
    *(ushort4*)(ygb + ((size_t)(b*SEQ) + t0 + t)*D_INNER + q*4) = o;
  }
}

extern "C" void kernel_launch(void* const* d_in, const int* in_sizes, int n_in,
                              void* d_out, int out_size, void* d_ws, size_t ws_size,
                              hipStream_t stream){
  const float* x0      = (const float*)d_in[0];
  const float* ln_w    = (const float*)d_in[1];
  const float* ln_b    = (const float*)d_in[2];
  const float* W_in    = (const float*)d_in[3];
  const float* conv_w  = (const float*)d_in[4];
  const float* conv_b  = (const float*)d_in[5];
  const float* dt_bias = (const float*)d_in[6];
  const float* A_log   = (const float*)d_in[7];
  const float* D_skip  = (const float*)d_in[8];
  const float* norm_w  = (const float*)d_in[9];
  const float* W_out   = (const float*)d_in[10];
  float* out = (float*)d_out;

  /* workspace (float units), ~91 MB */
  float* p    = (float*)d_ws;
  unsigned short* zxb = (unsigned short*)p;   p += (size_t)ROWS*ZXB_LD/2;
  float* dtraw = p;  p += (size_t)ROWS*8;
  float* cumb  = p;  p += (size_t)BATCH*NHEADS*SEQ;
  float* Dc    = p;  p += (size_t)BATCH*NHEADS*NC;
  unsigned short* ybuf = (unsigned short*)p;  p += (size_t)ROWS*D_INNER/2;
  unsigned short* ygb  = (unsigned short*)p;  p += (size_t)ROWS*D_INNER/2;
  unsigned short* Sb   = (unsigned short*)p;  p += (size_t)BATCH*NC*NHEADS*HEADDIM*D_STATE/2;
  unsigned short* Cb   = (unsigned short*)p;  p += (size_t)ROWS*D_STATE/2;
  bf16* Wt  = (bf16*)p; p += (size_t)NUM_LAYERS*NPAD_IN*D_MODEL/2;
  bf16* Wot = (bf16*)p;
  bf16* hnb = (bf16*)Sb;   /* alias: live ln -> gemm_in, dead before fused_scan */

  hipMemcpyAsync(out, x0, (size_t)ROWS*D_MODEL*sizeof(float),
                 hipMemcpyDeviceToDevice, stream);

  wconv_kernel<<<dim3(NPAD_IN/32, D_MODEL/32, NUM_LAYERS), dim3(32,8), 0, stream>>>(
      W_in, Wt, D_MODEL, D_IN_PROJ, NPAD_IN);
  wconv_kernel<<<dim3(NPAD_OUT/32, D_INNER/32, NUM_LAYERS), dim3(32,8), 0, stream>>>(
      W_out, Wot, D_INNER, D_MODEL, NPAD_OUT);

  for (int i=0;i<NUM_LAYERS;i++){
    ln_kernel<<<ROWS,128,0,stream>>>(out, ln_w+(size_t)i*D_MODEL, ln_b+(size_t)i*D_MODEL, hnb);
    mfma_gemm<1><<<dim3(NPAD_IN/128, ROWS/128), 256, 0, stream>>>(
        (const unsigned short*)hnb, (const unsigned short*)(Wt + (size_t)i*NPAD_IN*D_MODEL),
        nullptr, zxb, dtraw, D_IN_PROJ, D_MODEL, 0);
    fused_scan_kernel<<<BATCH*NC*4, 256, 0, stream>>>(
        zxb, dtraw, conv_w + (size_t)i*CONV_DIM*4, conv_b + (size_t)i*CONV_DIM,
        dt_bias+(size_t)i*NHEADS, A_log+(size_t)i*NHEADS, D_skip+(size_t)i*NHEADS,
        cumb, Dc, Cb, Sb, ybuf);
    combine_kernel<<<(BATCH*NHEADS*HEADDIM*16)/256, 256, 0, stream>>>(Sb, Dc);
    hinfuse_kernel<<<BATCH*NC, 256, 0, stream>>>(
        Cb, Sb, cumb, zxb, norm_w+(size_t)i*D_INNER, ybuf, ygb);
    mfma_gemm<0><<<dim3(NPAD_OUT/128, ROWS/128), 256, 0, stream>>>(
        (const unsigned short*)ygb, (const unsigned short*)(Wot + (size_t)i*NPAD_OUT*D_INNER),
        out, nullptr, nullptr, D_MODEL, D_INNER, D_MODEL);
  }
}